// Round 3
// baseline (351.879 us; speedup 1.0000x reference)
//
#include <hip/hip_runtime.h>
#include <math.h>

// MSTAGNN: N nodes, E edges (propagation), FE full edges (regression head).
// HC=64, HEADS=4, HEADC=DV=16, KHOP=3, NUM_T=128.
// R10: XCD-sliced hop. The 1KB M row is split into 8 x 128B slices; blocks
// handle (node-group, slice) with slice = blockIdx%8 so each slice is pinned
// to one XCD (round-robin dispatch) and its working set (N*128B = 2.56MB)
// fits the 4MB per-XCD L2. Hop-k slice writes pre-warm hop-k+1 slice reads
// on the same XCD. Per-slice H/C partials are combined once at the end
// (k_comb), which also fuses the Wo projection and edge-head P1/P2.

#define HC 64
#define HEADS 4
#define KHOP 3
#define NUM_T 128
#define MSZ 1024    // bytes per node M row (fp8)
#define SLOTS 64    // padded CSR slots per node
#define CST 1e-5f

typedef float f32x2 __attribute__((ext_vector_type(2)));

// ---- bf16 helpers (storage-only precision; accumulate in fp32) ----
__device__ __forceinline__ float bf2f(unsigned short s) { return __uint_as_float(((unsigned int)s) << 16); }
__device__ __forceinline__ float bfu_lo(unsigned int u) { return __uint_as_float(u << 16); }
__device__ __forceinline__ float bfu_hi(unsigned int u) { return __uint_as_float(u & 0xffff0000u); }
__device__ __forceinline__ unsigned short f2bf(float f) {
    unsigned int u = __float_as_uint(f);
    u = (u + 0x7fffu + ((u >> 16) & 1u)) >> 16;   // RTNE
    return (unsigned short)u;
}
// ---- fp8 e4m3 via HW pack/unpack (gfx950 OCP) ----
__device__ __forceinline__ unsigned int pack4fp8(float a, float b, float c, float d) {
    int r = __builtin_amdgcn_cvt_pk_fp8_f32(a, b, 0, false);       // bytes 0,1
    r = __builtin_amdgcn_cvt_pk_fp8_f32(c, d, r, true);            // bytes 2,3
    return (unsigned int)r;
}

// ---------------- padded-CSR fill: cnt[c]++ ; csr[c*64+k] = row ----------------
__global__ void k_fill(const int* __restrict__ row, const int* __restrict__ col,
                       int* __restrict__ cnt, int* __restrict__ csr, int E) {
    int e = blockIdx.x * 256 + threadIdx.x;
    if (e >= E) return;
    int c = col[e];
    int r = row[e];
    int k = atomicAdd(&cnt[c], 1);
    if (k < SLOTS) csr[c * SLOTS + k] = r;
}

// ------- misc: temb table (blocks 0..127, one tval each) + gamma (block 0)
//         + inv_deg (blocks 128+) -------
__global__ __launch_bounds__(256) void k_misc(
    const float* __restrict__ Wt1, const float* __restrict__ bt1,
    const float* __restrict__ Wt2, const float* __restrict__ bt2,
    const float* __restrict__ hopwise, const float* __restrict__ headwise,
    const int* __restrict__ cnt,
    float* __restrict__ gamma, float* __restrict__ table,
    float* __restrict__ inv_deg, int n) {
    if (blockIdx.x >= NUM_T) {
        int i = (blockIdx.x - NUM_T) * 256 + threadIdx.x;
        if (i < n) {
            int d = cnt[i];
            inv_deg[i] = (d > 0) ? 1.0f / (float)min(d, SLOTS) : 0.0f;
        }
        return;
    }
    if (blockIdx.x == 0 && threadIdx.x == 0) {
        for (int k = 0; k < KHOP; k++) {
            float m = -1e30f;
            for (int h2 = 0; h2 < HEADS; h2++) m = fmaxf(m, headwise[h2 * KHOP + k]);
            float ex[HEADS]; float s = 0.f;
            for (int h2 = 0; h2 < HEADS; h2++) { ex[h2] = expf(headwise[h2 * KHOP + k] - m); s += ex[h2]; }
            for (int h2 = 0; h2 < HEADS; h2++) gamma[k * HEADS + h2] = hopwise[k + 1] * ex[h2] / s;
        }
    }
    int t = threadIdx.x;
    int tval = blockIdx.x;                           // 0..127
    __shared__ float emb_s[64];
    __shared__ float z1_s[256];
    __shared__ float ps_s[4][64];
    if (t < 64) {
        float tt = (float)tval * 31.25f;             // 4000/128
        float e;
        if (t < 32) e = sinf(tt * expf(-0.2971077539347156f * (float)t));
        else        e = cosf(tt * expf(-0.2971077539347156f * (float)(t - 32)));
        emb_s[t] = e;
    }
    __syncthreads();
    {   // z1[t] = silu(emb . Wt1[:,t] + bt1[t])
        float acc = bt1[t];
        #pragma unroll 8
        for (int i = 0; i < 64; i++) acc += emb_s[i] * Wt1[i * 256 + t];
        z1_s[t] = acc / (1.f + expf(-acc));
    }
    __syncthreads();
    {   // out[j] = z1 . Wt2[:,j] + bt2[j], split over 4 partials
        int j = t & 63, p = t >> 6;
        float acc = 0.f;
        #pragma unroll 8
        for (int i = 0; i < 64; i++) acc += z1_s[p * 64 + i] * Wt2[(p * 64 + i) * 64 + j];
        ps_s[p][j] = acc;
    }
    __syncthreads();
    if (t < 64)
        table[tval * 64 + t] = ps_s[0][t] + ps_s[1][t] + ps_s[2][t] + ps_s[3][t] + bt2[t];
}

// ---- fused node kernel: h -> QKV -> Q, pre-scaled Kf0'(bf16), V(bf16) ----
__global__ __launch_bounds__(256) void k_node(
    const float* __restrict__ x, const int* __restrict__ time_steps,
    const float* __restrict__ temb, const float* __restrict__ Wi,
    const float* __restrict__ bi,
    const float* __restrict__ WQ, const float* __restrict__ bQ,
    const float* __restrict__ WK, const float* __restrict__ bK,
    const float* __restrict__ WV, const float* __restrict__ bV,
    const float* __restrict__ inv_deg,
    float* __restrict__ Q, unsigned short* __restrict__ Kf0,
    unsigned short* __restrict__ Vbuf, int n) {
    __shared__ float xs[16][128];                      // 8 KB
    __shared__ float hs[16][64];                       // 4 KB
    int j = threadIdx.x & 63;
    int slot = threadIdx.x >> 6;                       // wave id
    int nbase = blockIdx.x * 16;
    int nvalid = min(16, n - nbase);
    const float4* xg = (const float4*)(x + (size_t)nbase * 128);
    float4* xs4 = (float4*)&xs[0][0];
    for (int idx = threadIdx.x; idx < nvalid * 32; idx += 256) xs4[idx] = xg[idx];
    __syncthreads();
    int nl = slot * 4;
    {
        float acc[4];
        #pragma unroll
        for (int k = 0; k < 4; k++) acc[k] = 0.f;
        #pragma unroll 8
        for (int i = 0; i < 128; i++) {
            float w = Wi[i * 64 + j];
            #pragma unroll
            for (int k = 0; k < 4; k++) acc[k] += xs[nl + k][i] * w;
        }
        float bj = bi[j];
        #pragma unroll
        for (int k = 0; k < 4; k++) {
            int node = nbase + nl + k;
            float te = (node < n) ? temb[time_steps[node] * 64 + j] : 0.f;
            hs[nl + k][j] = fmaxf(acc[k] + bj + te, 0.f);
        }
    }
    __syncthreads();
    float aq[4], ak[4], av[4];
    #pragma unroll
    for (int k = 0; k < 4; k++) { aq[k] = bQ[j]; ak[k] = bK[j]; av[k] = bV[j]; }
    #pragma unroll 4
    for (int i = 0; i < 64; i++) {
        float wq = WQ[i * 64 + j], wk = WK[i * 64 + j], wv = WV[i * 64 + j];
        #pragma unroll
        for (int k = 0; k < 4; k++) {
            float hv = hs[nl + k][i];
            aq[k] += hv * wq; ak[k] += hv * wk; av[k] += hv * wv;
        }
    }
    #pragma unroll
    for (int k = 0; k < 4; k++) {
        int node = nbase + nl + k;
        if (node < n) {
            float q  = 1.f + ((aq[k] > 0.f) ? aq[k] : (expf(aq[k]) - 1.f));
            float kf = 1.f + ((ak[k] > 0.f) ? ak[k] : (expf(ak[k]) - 1.f));
            float inv = inv_deg[node];
            Q[(size_t)node * 64 + j] = q;
            Kf0[(size_t)node * 64 + j] = f2bf(kf * inv);       // pre-scaled Kf'
            Vbuf[(size_t)node * 64 + j] = f2bf(av[k]);
        }
    }
}

// ---- sliced hop: block = (node-group of 16, slice); slice = blockIdx%8 -> XCD.
// Slice s covers head h=s>>1, i-half ih=s&1 (128B of the 1KB row, all j).
// Wave = 4 nodes x 16 lanes; lane = (i_loc = ell>>1, jh = ell&1): 8B of M per
// edge (j = jh*8 .. +8 for row i = ih*8+i_loc). CSR slots live in 4 regs,
// edge source via __shfl. Writes per-slice M/Kf and H/C partials (combined
// later in k_comb). MODE 0: outer product from Kf'/V. MODE 1: dense M rows.
template<int MODE>
__global__ __launch_bounds__(256) void k_hop(
    const unsigned char* __restrict__ Mold, const unsigned short* __restrict__ Kfold,
    const unsigned short* __restrict__ Vb,
    const int* __restrict__ cnt, const int* __restrict__ csr,
    const float* __restrict__ inv_deg, const float* __restrict__ Q,
    unsigned char* __restrict__ Mnew, unsigned short* __restrict__ Kfnew,
    float* __restrict__ Hp, float* __restrict__ Cp,
    int hop, int write_out, int n) {
    int lane = threadIdx.x & 63;
    int wv   = threadIdx.x >> 6;
    int slice = blockIdx.x & 7;
    int ngrp  = blockIdx.x >> 3;
    int ell   = lane & 15;
    int gbase = lane & 48;
    int node  = ngrp * 16 + wv * 4 + (lane >> 4);
    int h = slice >> 1, ib = (slice & 1) * 8;
    int i_loc = ell >> 1, jh = ell & 1;
    bool valid = node < n;
    int deg = 0; int s0 = 0, s1 = 0, s2 = 0, s3 = 0; float qv = 0.f;
    if (valid) {
        deg = min(__builtin_nontemporal_load(cnt + node), SLOTS);
        const int* cb = csr + (size_t)node * SLOTS;
        s0 = __builtin_nontemporal_load(cb + ell);
        s1 = __builtin_nontemporal_load(cb + 16 + ell);
        s2 = __builtin_nontemporal_load(cb + 32 + ell);
        s3 = __builtin_nontemporal_load(cb + 48 + ell);
        qv = Q[(size_t)node * 64 + h * 16 + ib + i_loc];
    }
    int dm = max(deg, __shfl_xor(deg, 16));
    dm = max(dm, __shfl_xor(dm, 32));
    int degU = __builtin_amdgcn_readfirstlane(dm);

    float acc[8];
    #pragma unroll
    for (int t = 0; t < 8; t++) acc[t] = 0.f;
    float kacc = 0.f;

    constexpr int SUB = (MODE == 0) ? 8 : 16;
    #pragma unroll
    for (int blk = 0; blk < 4; blk++) {
        if (blk * 16 >= degU) break;                 // wave-uniform
        int sreg = (blk == 0) ? s0 : (blk == 1) ? s1 : (blk == 2) ? s2 : s3;
        #pragma unroll
        for (int sb = 0; sb < 16 / SUB; sb++) {
            unsigned int kr[SUB];
            uint2 mv[(MODE == 1) ? SUB : 1];
            uint4 vvv[(MODE == 0) ? SUB : 1];
            #pragma unroll
            for (int t = 0; t < SUB; t++) {
                int sl = sb * SUB + t;               // slot within reg blk
                int q = blk * 16 + sl;
                int sv = __shfl(sreg, gbase + sl);
                kr[t] = 0u;
                if constexpr (MODE == 0) { vvv[t] = make_uint4(0, 0, 0, 0); }
                else { mv[t].x = 0u; mv[t].y = 0u; }
                if (q < deg) {
                    kr[t] = (unsigned int)Kfold[(size_t)sv * 64 + h * 16 + ib + i_loc];
                    if constexpr (MODE == 0)
                        vvv[t] = *(const uint4*)(Vb + (size_t)sv * 64 + h * 16 + jh * 8);
                    else
                        mv[t] = *(const uint2*)(Mold + (size_t)sv * MSZ + slice * 128 + ell * 8);
                }
            }
            #pragma unroll
            for (int t = 0; t < SUB; t++) {
                float kf = bf2f((unsigned short)kr[t]);
                kacc += kf;
                if constexpr (MODE == 0) {
                    acc[0] += kf * bfu_lo(vvv[t].x); acc[1] += kf * bfu_hi(vvv[t].x);
                    acc[2] += kf * bfu_lo(vvv[t].y); acc[3] += kf * bfu_hi(vvv[t].y);
                    acc[4] += kf * bfu_lo(vvv[t].z); acc[5] += kf * bfu_hi(vvv[t].z);
                    acc[6] += kf * bfu_lo(vvv[t].w); acc[7] += kf * bfu_hi(vvv[t].w);
                } else {
                    f32x2 p;
                    p = __builtin_amdgcn_cvt_pk_f32_fp8((int)mv[t].x, false); acc[0] += p.x; acc[1] += p.y;
                    p = __builtin_amdgcn_cvt_pk_f32_fp8((int)mv[t].x, true);  acc[2] += p.x; acc[3] += p.y;
                    p = __builtin_amdgcn_cvt_pk_f32_fp8((int)mv[t].y, false); acc[4] += p.x; acc[5] += p.y;
                    p = __builtin_amdgcn_cvt_pk_f32_fp8((int)mv[t].y, true);  acc[6] += p.x; acc[7] += p.y;
                }
            }
        }
    }

    if (valid && write_out) {
        float inv = inv_deg[node];
        uint2 st;
        st.x = pack4fp8(acc[0] * inv, acc[1] * inv, acc[2] * inv, acc[3] * inv);
        st.y = pack4fp8(acc[4] * inv, acc[5] * inv, acc[6] * inv, acc[7] * inv);
        *(uint2*)(Mnew + (size_t)node * MSZ + slice * 128 + ell * 8) = st;
        if (jh == 0) Kfnew[(size_t)node * 64 + h * 16 + ib + i_loc] = f2bf(kacc * inv);
    }

    // partial H[jh*8 + k] = sum_{i_loc} Q[h, ib+i_loc] * acc_i[k]  (xor 2,4,8)
    float w[8];
    #pragma unroll
    for (int k = 0; k < 8; k++) w[k] = qv * acc[k];
    #pragma unroll
    for (int m = 2; m <= 8; m <<= 1) {
        #pragma unroll
        for (int k = 0; k < 8; k++) w[k] += __shfl_xor(w[k], m);
    }
    // partial C = sum_{i_loc} Q*kacc (count jh==0 copies only)
    float ck = (jh == 0) ? qv * kacc : 0.f;
    ck += __shfl_xor(ck, 1); ck += __shfl_xor(ck, 2);
    ck += __shfl_xor(ck, 4); ck += __shfl_xor(ck, 8);

    if (valid) {
        float* hpb = Hp + ((size_t)hop * n + node) * 128 + slice * 16;
        if (ell < 2) {   // ell==0 -> jh 0 (j 0..7), ell==1 -> jh 1 (j 8..15)
            *(float4*)(hpb + jh * 8)     = make_float4(w[0], w[1], w[2], w[3]);
            *(float4*)(hpb + jh * 8 + 4) = make_float4(w[4], w[5], w[6], w[7]);
        }
        if (ell == 0) Cp[((size_t)hop * n + node) * 8 + slice] = ck;
    }
}

// ---- combine: hid = hopwise0*V + sum_hops gamma*H/C ; fused Wo proj + P1/P2 ----
__global__ __launch_bounds__(256) void k_comb(
    const unsigned short* __restrict__ Vb,
    const float* __restrict__ Hp, const float* __restrict__ Cp,
    const float* __restrict__ gamma, const float* __restrict__ hopwise,
    const float* __restrict__ Wo, const float* __restrict__ bo,
    const float* __restrict__ Wf1,
    float* __restrict__ out16, float* __restrict__ Pbuf, int n) {
    int lane = threadIdx.x & 63;
    int node = blockIdx.x * 4 + (threadIdx.x >> 6);
    if (node >= n) return;
    int h = lane >> 4, j = lane & 15;
    float hid = hopwise[0] * bf2f(Vb[(size_t)node * 64 + lane]);
    #pragma unroll
    for (int hop = 0; hop < KHOP; hop++) {
        const float* hpb = Hp + ((size_t)hop * n + node) * 128;
        const float* cpb = Cp + ((size_t)hop * n + node) * 8;
        float Hs = hpb[(2 * h) * 16 + j] + hpb[(2 * h + 1) * 16 + j];
        float Cs = cpb[2 * h] + cpb[2 * h + 1] + CST;
        hid += gamma[hop * HEADS + h] * Hs / Cs;
    }
    // Wo projection: out16 = hid(64) @ Wo(64x16) + bo, reduced over 64 lanes
    const float4* wop = (const float4*)(Wo + lane * 16);
    float4 wo0 = wop[0], wo1 = wop[1], wo2 = wop[2], wo3 = wop[3];
    float v[16];
    v[0] = hid * wo0.x;  v[1] = hid * wo0.y;  v[2] = hid * wo0.z;  v[3] = hid * wo0.w;
    v[4] = hid * wo1.x;  v[5] = hid * wo1.y;  v[6] = hid * wo1.z;  v[7] = hid * wo1.w;
    v[8] = hid * wo2.x;  v[9] = hid * wo2.y;  v[10] = hid * wo2.z; v[11] = hid * wo2.w;
    v[12] = hid * wo3.x; v[13] = hid * wo3.y; v[14] = hid * wo3.z; v[15] = hid * wo3.w;
    #pragma unroll
    for (int m = 32; m >= 1; m >>= 1) {
        #pragma unroll
        for (int o = 0; o < 16; o++) v[o] += __shfl_xor(v[o], m);
    }
    #pragma unroll
    for (int o = 0; o < 16; o++) v[o] += bo[o];
    if (lane == 0) {
        float4* op = (float4*)(out16 + (size_t)node * 16);
        op[0] = make_float4(v[0],  v[1],  v[2],  v[3]);
        op[1] = make_float4(v[4],  v[5],  v[6],  v[7]);
        op[2] = make_float4(v[8],  v[9],  v[10], v[11]);
        op[3] = make_float4(v[12], v[13], v[14], v[15]);
    }
    if (lane < 32) {
        int o = lane & 15, half = lane >> 4;
        const float* wf = Wf1 + (size_t)(half * 16) * 16 + o;
        float p = 0.f;
        #pragma unroll
        for (int i = 0; i < 16; i++) p += v[i] * wf[i * 16];
        Pbuf[(size_t)node * 32 + lane] = p;         // [n][0:16]=P1(src), [16:32]=P2(dst)
    }
}

// ---------------- edge regression head: z = P1[s] + P2[d] + b1 ----------------
__global__ __launch_bounds__(256) void k_edge(
    const int* __restrict__ src, const int* __restrict__ dst,
    const float* __restrict__ Pbuf,
    const float* __restrict__ bf1, const float* __restrict__ Wf2,
    const float* __restrict__ bf2,
    float* __restrict__ out, int fe) {
    __shared__ float b1[16];
    __shared__ float w2[16];
    __shared__ float b2s;
    int t = threadIdx.x;
    if (t < 16) { b1[t] = bf1[t]; w2[t] = Wf2[t]; }
    if (t == 0) b2s = bf2[0];
    __syncthreads();
    int e = blockIdx.x * 256 + t;
    if (e >= fe) return;
    int s = src[e], d = dst[e];
    const float4* p1 = (const float4*)(Pbuf + (size_t)s * 32);
    const float4* p2 = (const float4*)(Pbuf + (size_t)d * 32 + 16);
    float z[16];
    #pragma unroll
    for (int q = 0; q < 4; q++) {
        float4 a = p1[q]; float4 b = p2[q];
        z[q * 4 + 0] = a.x + b.x; z[q * 4 + 1] = a.y + b.y;
        z[q * 4 + 2] = a.z + b.z; z[q * 4 + 3] = a.w + b.w;
    }
    float acc = b2s;
    #pragma unroll
    for (int o = 0; o < 16; o++) {
        float zz = z[o] + b1[o];
        zz = zz / (1.f + expf(-zz));       // silu
        acc += zz * w2[o];
    }
    out[e] = acc;
}

extern "C" void kernel_launch(void* const* d_in, const int* in_sizes, int n_in,
                              void* d_out, int out_size, void* d_ws, size_t ws_size,
                              hipStream_t stream) {
    const float* x        = (const float*)d_in[0];
    const int*   eidx     = (const int*)d_in[1];
    const int*   feidx    = (const int*)d_in[2];
    const int*   tsteps   = (const int*)d_in[3];
    const float* Wi  = (const float*)d_in[4];
    const float* bi  = (const float*)d_in[5];
    const float* Wt1 = (const float*)d_in[6];
    const float* bt1 = (const float*)d_in[7];
    const float* Wt2 = (const float*)d_in[8];
    const float* bt2 = (const float*)d_in[9];
    const float* WQ  = (const float*)d_in[10];
    const float* bQ  = (const float*)d_in[11];
    const float* WK  = (const float*)d_in[12];
    const float* bK  = (const float*)d_in[13];
    const float* WV  = (const float*)d_in[14];
    const float* bV  = (const float*)d_in[15];
    const float* Wo  = (const float*)d_in[16];
    const float* bo  = (const float*)d_in[17];
    const float* hopwise  = (const float*)d_in[18];
    const float* headwise = (const float*)d_in[19];
    const float* Wf1 = (const float*)d_in[20];
    const float* bf1 = (const float*)d_in[21];
    const float* Wf2 = (const float*)d_in[22];
    const float* bf2 = (const float*)d_in[23];

    const int N  = in_sizes[3];
    const int E  = in_sizes[1] / 2;
    const int FE = in_sizes[2] / 2;
    const int* row = eidx;           // [0,:]
    const int* col = eidx + E;       // [1,:]
    const int* fsrc = feidx;
    const int* fdst = feidx + FE;

    // ---- workspace carve-up (256B aligned) ----
    char* ws = (char*)d_ws;
    size_t off = 0;
    auto alloc = [&](size_t bytes) -> char* {
        char* p = ws + off;
        off = (off + bytes + 255) & ~(size_t)255;
        return p;
    };
    float* gamma     = (float*)alloc(KHOP * HEADS * sizeof(float));
    int*   cnt       = (int*)alloc((size_t)N * 4);
    int*   csr       = (int*)alloc((size_t)N * SLOTS * 4);
    float* inv_deg   = (float*)alloc((size_t)N * 4);
    float* temb      = (float*)alloc((size_t)NUM_T * HC * 4);
    float* Qbuf      = (float*)alloc((size_t)N * HC * 4);
    unsigned short* Kf0  = (unsigned short*)alloc((size_t)N * HC * 2);
    unsigned short* Kf_a = (unsigned short*)alloc((size_t)N * HC * 2);
    unsigned short* Kf_b = (unsigned short*)alloc((size_t)N * HC * 2);
    unsigned short* Vbuf = (unsigned short*)alloc((size_t)N * HC * 2);
    unsigned char* M_a = (unsigned char*)alloc((size_t)N * MSZ);
    unsigned char* M_b = (unsigned char*)alloc((size_t)N * MSZ);
    float* Hp        = (float*)alloc((size_t)KHOP * N * 128 * 4);
    float* Cp        = (float*)alloc((size_t)KHOP * N * 8 * 4);
    float* Pbuf      = (float*)alloc((size_t)N * 32 * 4);
    (void)ws_size;

    float* out_edges = (float*)d_out;            // [FE]
    float* out_hid16 = (float*)d_out + FE;       // [N,16]

    const int miscBlocks = NUM_T + (N + 255) / 256;
    const int hopBlocks = 8 * ((N + 15) / 16);   // slice = blockIdx % 8 -> XCD

    (void)hipMemsetAsync(cnt, 0, (size_t)N * 4, stream);
    k_fill<<<(E + 255) / 256, 256, 0, stream>>>(row, col, cnt, csr, E);
    k_misc<<<miscBlocks, 256, 0, stream>>>(Wt1, bt1, Wt2, bt2, hopwise, headwise,
                                           cnt, gamma, temb, inv_deg, N);
    k_node<<<(N + 15) / 16, 256, 0, stream>>>(x, tsteps, temb, Wi, bi,
                                              WQ, bQ, WK, bK, WV, bV, inv_deg,
                                              Qbuf, Kf0, Vbuf, N);
    // hop 0: outer-product gather (Kf0', V) -> M_a', Kf_a' + partials[0]
    k_hop<0><<<hopBlocks, 256, 0, stream>>>(nullptr, Kf0, Vbuf, cnt, csr, inv_deg, Qbuf,
                                            M_a, Kf_a, Hp, Cp, 0, 1, N);
    // hop 1: dense M_a' -> M_b' + partials[1]
    k_hop<1><<<hopBlocks, 256, 0, stream>>>(M_a, Kf_a, nullptr, cnt, csr, inv_deg, Qbuf,
                                            M_b, Kf_b, Hp, Cp, 1, 1, N);
    // hop 2: dense gather M_b', no M/Kf write, partials[2]
    k_hop<1><<<hopBlocks, 256, 0, stream>>>(M_b, Kf_b, nullptr, cnt, csr, inv_deg, Qbuf,
                                            M_a, Kf_a, Hp, Cp, 2, 0, N);
    // combine partials -> hidden -> Wo projection -> out16 + P1/P2
    k_comb<<<(N + 3) / 4, 256, 0, stream>>>(Vbuf, Hp, Cp, gamma, hopwise,
                                            Wo, bo, Wf1, out_hid16, Pbuf, N);
    k_edge<<<(FE + 255) / 256, 256, 0, stream>>>(fsrc, fdst, Pbuf, bf1, Wf2, bf2,
                                                 out_edges, FE);
}

// Round 5
// 297.558 us; speedup vs baseline: 1.1826x; 1.1826x over previous
//
#include <hip/hip_runtime.h>
#include <math.h>

// MSTAGNN: N nodes, E edges (propagation), FE full edges (regression head).
// HC=64, HEADS=4, HEADC=DV=16, KHOP=3, NUM_T=128.
// R11b = R9 (best verified: wave-per-node pull hops, guarded tails) with hop2
// converted from PULL (1152 B/edge on the ~2.1 TB/s scattered-miss wall) to
// PUSH: stream each source's M2' row once (nontemporal), gather dest Q
// (bf16, 128 B/edge), scatter H/C via coalesced f32 atomicAdd (256 B/edge).
// Final-hop epilogue (Wo proj + edge-head P1/P2 factorization) moves to
// k_comb. Hop0 outer-product and hop1 dense pull are unchanged from R9.
// (R11 fix: nontemporal loads use ext_vector_type, not HIP uint4 class.)

#define HC 64
#define HEADS 4
#define KHOP 3
#define NUM_T 128
#define MSZ 1024    // bytes per node M row (fp8)
#define SLOTS 64    // padded CSR slots per node
#define CST 1e-5f

typedef float f32x2 __attribute__((ext_vector_type(2)));
typedef unsigned int u32x4 __attribute__((ext_vector_type(4)));

// ---- bf16 helpers (storage-only precision; accumulate in fp32) ----
__device__ __forceinline__ float bf2f(unsigned short s) { return __uint_as_float(((unsigned int)s) << 16); }
__device__ __forceinline__ float bfu_lo(unsigned int u) { return __uint_as_float(u << 16); }
__device__ __forceinline__ float bfu_hi(unsigned int u) { return __uint_as_float(u & 0xffff0000u); }
__device__ __forceinline__ unsigned short f2bf(float f) {
    unsigned int u = __float_as_uint(f);
    u = (u + 0x7fffu + ((u >> 16) & 1u)) >> 16;   // RTNE
    return (unsigned short)u;
}
// ---- fp8 e4m3 via HW pack/unpack (gfx950 OCP) ----
__device__ __forceinline__ unsigned int pack4fp8(float a, float b, float c, float d) {
    int r = __builtin_amdgcn_cvt_pk_fp8_f32(a, b, 0, false);       // bytes 0,1
    r = __builtin_amdgcn_cvt_pk_fp8_f32(c, d, r, true);            // bytes 2,3
    return (unsigned int)r;
}

// ------- dual padded-CSR fill: in-CSR (by col) for pull, out-CSR (by row) for push -------
__global__ void k_fill(const int* __restrict__ row, const int* __restrict__ col,
                       int* __restrict__ cnt, int* __restrict__ csr,
                       int* __restrict__ ocnt, int* __restrict__ ocsr, int E) {
    int e = blockIdx.x * 256 + threadIdx.x;
    if (e >= E) return;
    int c = col[e];
    int r = row[e];
    int k = atomicAdd(&cnt[c], 1);
    if (k < SLOTS) csr[c * SLOTS + k] = r;
    int k2 = atomicAdd(&ocnt[r], 1);
    if (k2 < SLOTS) ocsr[r * SLOTS + k2] = c;
}

// ------- misc: temb table (blocks 0..127, one tval each) + gamma (block 0)
//         + inv_deg (blocks 128+) -------
__global__ __launch_bounds__(256) void k_misc(
    const float* __restrict__ Wt1, const float* __restrict__ bt1,
    const float* __restrict__ Wt2, const float* __restrict__ bt2,
    const float* __restrict__ hopwise, const float* __restrict__ headwise,
    const int* __restrict__ cnt,
    float* __restrict__ gamma, float* __restrict__ table,
    float* __restrict__ inv_deg, int n) {
    if (blockIdx.x >= NUM_T) {
        int i = (blockIdx.x - NUM_T) * 256 + threadIdx.x;
        if (i < n) {
            int d = cnt[i];
            inv_deg[i] = (d > 0) ? 1.0f / (float)min(d, SLOTS) : 0.0f;
        }
        return;
    }
    if (blockIdx.x == 0 && threadIdx.x == 0) {
        for (int k = 0; k < KHOP; k++) {
            float m = -1e30f;
            for (int h2 = 0; h2 < HEADS; h2++) m = fmaxf(m, headwise[h2 * KHOP + k]);
            float ex[HEADS]; float s = 0.f;
            for (int h2 = 0; h2 < HEADS; h2++) { ex[h2] = expf(headwise[h2 * KHOP + k] - m); s += ex[h2]; }
            for (int h2 = 0; h2 < HEADS; h2++) gamma[k * HEADS + h2] = hopwise[k + 1] * ex[h2] / s;
        }
    }
    int t = threadIdx.x;
    int tval = blockIdx.x;                           // 0..127
    __shared__ float emb_s[64];
    __shared__ float z1_s[256];
    __shared__ float ps_s[4][64];
    if (t < 64) {
        float tt = (float)tval * 31.25f;             // 4000/128
        float e;
        if (t < 32) e = sinf(tt * expf(-0.2971077539347156f * (float)t));
        else        e = cosf(tt * expf(-0.2971077539347156f * (float)(t - 32)));
        emb_s[t] = e;
    }
    __syncthreads();
    {   // z1[t] = silu(emb . Wt1[:,t] + bt1[t])
        float acc = bt1[t];
        #pragma unroll 8
        for (int i = 0; i < 64; i++) acc += emb_s[i] * Wt1[i * 256 + t];
        z1_s[t] = acc / (1.f + expf(-acc));
    }
    __syncthreads();
    {   // out[j] = z1 . Wt2[:,j] + bt2[j], split over 4 partials
        int j = t & 63, p = t >> 6;
        float acc = 0.f;
        #pragma unroll 8
        for (int i = 0; i < 64; i++) acc += z1_s[p * 64 + i] * Wt2[(p * 64 + i) * 64 + j];
        ps_s[p][j] = acc;
    }
    __syncthreads();
    if (t < 64)
        table[tval * 64 + t] = ps_s[0][t] + ps_s[1][t] + ps_s[2][t] + ps_s[3][t] + bt2[t];
}

// ---- fused node kernel: h -> QKV -> Q(f32 + bf16), pre-scaled Kf0'(bf16),
//      V(bf16), hidden init ----
__global__ __launch_bounds__(256) void k_node(
    const float* __restrict__ x, const int* __restrict__ time_steps,
    const float* __restrict__ temb, const float* __restrict__ Wi,
    const float* __restrict__ bi,
    const float* __restrict__ WQ, const float* __restrict__ bQ,
    const float* __restrict__ WK, const float* __restrict__ bK,
    const float* __restrict__ WV, const float* __restrict__ bV,
    const float* __restrict__ hopwise, const float* __restrict__ inv_deg,
    float* __restrict__ Q, unsigned short* __restrict__ Qbf,
    unsigned short* __restrict__ Kf0,
    unsigned short* __restrict__ Vbuf, float* __restrict__ hidden, int n) {
    __shared__ float xs[16][128];                      // 8 KB
    __shared__ float hs[16][64];                       // 4 KB
    int j = threadIdx.x & 63;
    int slot = threadIdx.x >> 6;                       // wave id
    int nbase = blockIdx.x * 16;
    int nvalid = min(16, n - nbase);
    const float4* xg = (const float4*)(x + (size_t)nbase * 128);
    float4* xs4 = (float4*)&xs[0][0];
    for (int idx = threadIdx.x; idx < nvalid * 32; idx += 256) xs4[idx] = xg[idx];
    __syncthreads();
    int nl = slot * 4;
    {
        float acc[4];
        #pragma unroll
        for (int k = 0; k < 4; k++) acc[k] = 0.f;
        #pragma unroll 8
        for (int i = 0; i < 128; i++) {
            float w = Wi[i * 64 + j];
            #pragma unroll
            for (int k = 0; k < 4; k++) acc[k] += xs[nl + k][i] * w;
        }
        float bj = bi[j];
        #pragma unroll
        for (int k = 0; k < 4; k++) {
            int node = nbase + nl + k;
            float te = (node < n) ? temb[time_steps[node] * 64 + j] : 0.f;
            hs[nl + k][j] = fmaxf(acc[k] + bj + te, 0.f);
        }
    }
    __syncthreads();
    float aq[4], ak[4], av[4];
    #pragma unroll
    for (int k = 0; k < 4; k++) { aq[k] = bQ[j]; ak[k] = bK[j]; av[k] = bV[j]; }
    #pragma unroll 4
    for (int i = 0; i < 64; i++) {
        float wq = WQ[i * 64 + j], wk = WK[i * 64 + j], wv = WV[i * 64 + j];
        #pragma unroll
        for (int k = 0; k < 4; k++) {
            float hv = hs[nl + k][i];
            aq[k] += hv * wq; ak[k] += hv * wk; av[k] += hv * wv;
        }
    }
    float h0 = hopwise[0];
    #pragma unroll
    for (int k = 0; k < 4; k++) {
        int node = nbase + nl + k;
        if (node < n) {
            float q  = 1.f + ((aq[k] > 0.f) ? aq[k] : (expf(aq[k]) - 1.f));
            float kf = 1.f + ((ak[k] > 0.f) ? ak[k] : (expf(ak[k]) - 1.f));
            float inv = inv_deg[node];
            Q[(size_t)node * 64 + j] = q;
            Qbf[(size_t)node * 64 + j] = f2bf(q);
            Kf0[(size_t)node * 64 + j] = f2bf(kf * inv);       // pre-scaled Kf'
            Vbuf[(size_t)node * 64 + j] = f2bf(av[k]);
            hidden[(size_t)node * 64 + j] = av[k] * h0;
        }
    }
}

// ---- pull hop (hops 0,1): wave-per-node (64 lanes), no LDS, no barriers;
// 2 nodes/block (128 thr). MODE 0: outer-product from Kf'(bf16)+V(bf16).
// MODE 1: dense gather from M(fp8) rows. Always writes M'/Kf' and hidden.
template<int MODE>
__global__ __launch_bounds__(128) void k_hop(
    const unsigned char* __restrict__ Mold, const unsigned short* __restrict__ Kfold,
    const unsigned short* __restrict__ Vbuf,
    const int* __restrict__ cnt, const int* __restrict__ csr,
    const float* __restrict__ inv_deg, const float* __restrict__ Q,
    const float* __restrict__ gamma,
    unsigned char* __restrict__ Mnew, unsigned short* __restrict__ Kfnew,
    float* __restrict__ hidden, int hop, int n) {
    constexpr int DEPTH = (MODE == 0) ? 4 : 8;
    int lane = threadIdx.x & 63;
    int node = blockIdx.x * 2 + (threadIdx.x >> 6);
    if (node >= n) return;
    int grp = lane >> 4;                               // head h
    int deg = min(cnt[node], SLOTS);
    int sidx = csr[(size_t)node * SLOTS + lane];       // all 64 slots, one load
    float qv = Q[(size_t)node * 64 + lane];
    size_t hoff = (size_t)node * 64 + lane;
    float hid_in = hidden[hoff];
    int degU = __builtin_amdgcn_readfirstlane(deg);
    float acc[16];
    #pragma unroll
    for (int t = 0; t < 16; t++) acc[t] = 0.f;
    float kacc = 0.f;

    int d = 0;
    for (; d + DEPTH <= degU; d += DEPTH) {
        unsigned short kraw[DEPTH];
        uint4 m0[DEPTH], m1[DEPTH];
        #pragma unroll
        for (int t = 0; t < DEPTH; t++) {
            int s = __builtin_amdgcn_readlane(sidx, d + t);   // SGPR base
            kraw[t] = Kfold[(size_t)s * 64 + lane];
            if constexpr (MODE == 0) {
                const uint4* vp = (const uint4*)((const unsigned char*)Vbuf + (size_t)s * 128 + grp * 32);
                m0[t] = vp[0]; m1[t] = vp[1];
            } else {
                m0[t] = *(const uint4*)(Mold + (size_t)s * MSZ + lane * 16);
            }
        }
        #pragma unroll
        for (int t = 0; t < DEPTH; t++) {
            float kf = bf2f(kraw[t]);
            kacc += kf;
            if constexpr (MODE == 0) {
                acc[0]  = fmaf(kf, bfu_lo(m0[t].x), acc[0]);
                acc[1]  = fmaf(kf, bfu_hi(m0[t].x), acc[1]);
                acc[2]  = fmaf(kf, bfu_lo(m0[t].y), acc[2]);
                acc[3]  = fmaf(kf, bfu_hi(m0[t].y), acc[3]);
                acc[4]  = fmaf(kf, bfu_lo(m0[t].z), acc[4]);
                acc[5]  = fmaf(kf, bfu_hi(m0[t].z), acc[5]);
                acc[6]  = fmaf(kf, bfu_lo(m0[t].w), acc[6]);
                acc[7]  = fmaf(kf, bfu_hi(m0[t].w), acc[7]);
                acc[8]  = fmaf(kf, bfu_lo(m1[t].x), acc[8]);
                acc[9]  = fmaf(kf, bfu_hi(m1[t].x), acc[9]);
                acc[10] = fmaf(kf, bfu_lo(m1[t].y), acc[10]);
                acc[11] = fmaf(kf, bfu_hi(m1[t].y), acc[11]);
                acc[12] = fmaf(kf, bfu_lo(m1[t].z), acc[12]);
                acc[13] = fmaf(kf, bfu_hi(m1[t].z), acc[13]);
                acc[14] = fmaf(kf, bfu_lo(m1[t].w), acc[14]);
                acc[15] = fmaf(kf, bfu_hi(m1[t].w), acc[15]);
            } else {
                f32x2 p;
                p = __builtin_amdgcn_cvt_pk_f32_fp8((int)m0[t].x, false); acc[0]  += p.x; acc[1]  += p.y;
                p = __builtin_amdgcn_cvt_pk_f32_fp8((int)m0[t].x, true);  acc[2]  += p.x; acc[3]  += p.y;
                p = __builtin_amdgcn_cvt_pk_f32_fp8((int)m0[t].y, false); acc[4]  += p.x; acc[5]  += p.y;
                p = __builtin_amdgcn_cvt_pk_f32_fp8((int)m0[t].y, true);  acc[6]  += p.x; acc[7]  += p.y;
                p = __builtin_amdgcn_cvt_pk_f32_fp8((int)m0[t].z, false); acc[8]  += p.x; acc[9]  += p.y;
                p = __builtin_amdgcn_cvt_pk_f32_fp8((int)m0[t].z, true);  acc[10] += p.x; acc[11] += p.y;
                p = __builtin_amdgcn_cvt_pk_f32_fp8((int)m0[t].w, false); acc[12] += p.x; acc[13] += p.y;
                p = __builtin_amdgcn_cvt_pk_f32_fp8((int)m0[t].w, true);  acc[14] += p.x; acc[15] += p.y;
            }
        }
    }
    // exact tail: slots guarded by wave-uniform branches (no dup loads)
    if (d < degU) {
        int rem = degU - d;                            // 1..DEPTH-1
        unsigned short kraw[DEPTH];
        uint4 m0[DEPTH], m1[DEPTH];
        #pragma unroll
        for (int t = 0; t < DEPTH - 1; t++) {
            if (t < rem) {
                int s = __builtin_amdgcn_readlane(sidx, d + t);
                kraw[t] = Kfold[(size_t)s * 64 + lane];
                if constexpr (MODE == 0) {
                    const uint4* vp = (const uint4*)((const unsigned char*)Vbuf + (size_t)s * 128 + grp * 32);
                    m0[t] = vp[0]; m1[t] = vp[1];
                } else {
                    m0[t] = *(const uint4*)(Mold + (size_t)s * MSZ + lane * 16);
                }
            }
        }
        #pragma unroll
        for (int t = 0; t < DEPTH - 1; t++) {
            if (t < rem) {
                float kf = bf2f(kraw[t]);
                kacc += kf;
                if constexpr (MODE == 0) {
                    acc[0]  = fmaf(kf, bfu_lo(m0[t].x), acc[0]);
                    acc[1]  = fmaf(kf, bfu_hi(m0[t].x), acc[1]);
                    acc[2]  = fmaf(kf, bfu_lo(m0[t].y), acc[2]);
                    acc[3]  = fmaf(kf, bfu_hi(m0[t].y), acc[3]);
                    acc[4]  = fmaf(kf, bfu_lo(m0[t].z), acc[4]);
                    acc[5]  = fmaf(kf, bfu_hi(m0[t].z), acc[5]);
                    acc[6]  = fmaf(kf, bfu_lo(m0[t].w), acc[6]);
                    acc[7]  = fmaf(kf, bfu_hi(m0[t].w), acc[7]);
                    acc[8]  = fmaf(kf, bfu_lo(m1[t].x), acc[8]);
                    acc[9]  = fmaf(kf, bfu_hi(m1[t].x), acc[9]);
                    acc[10] = fmaf(kf, bfu_lo(m1[t].y), acc[10]);
                    acc[11] = fmaf(kf, bfu_hi(m1[t].y), acc[11]);
                    acc[12] = fmaf(kf, bfu_lo(m1[t].z), acc[12]);
                    acc[13] = fmaf(kf, bfu_hi(m1[t].z), acc[13]);
                    acc[14] = fmaf(kf, bfu_lo(m1[t].w), acc[14]);
                    acc[15] = fmaf(kf, bfu_hi(m1[t].w), acc[15]);
                } else {
                    f32x2 p;
                    p = __builtin_amdgcn_cvt_pk_f32_fp8((int)m0[t].x, false); acc[0]  += p.x; acc[1]  += p.y;
                    p = __builtin_amdgcn_cvt_pk_f32_fp8((int)m0[t].x, true);  acc[2]  += p.x; acc[3]  += p.y;
                    p = __builtin_amdgcn_cvt_pk_f32_fp8((int)m0[t].y, false); acc[4]  += p.x; acc[5]  += p.y;
                    p = __builtin_amdgcn_cvt_pk_f32_fp8((int)m0[t].y, true);  acc[6]  += p.x; acc[7]  += p.y;
                    p = __builtin_amdgcn_cvt_pk_f32_fp8((int)m0[t].z, false); acc[8]  += p.x; acc[9]  += p.y;
                    p = __builtin_amdgcn_cvt_pk_f32_fp8((int)m0[t].z, true);  acc[10] += p.x; acc[11] += p.y;
                    p = __builtin_amdgcn_cvt_pk_f32_fp8((int)m0[t].w, false); acc[12] += p.x; acc[13] += p.y;
                    p = __builtin_amdgcn_cvt_pk_f32_fp8((int)m0[t].w, true);  acc[14] += p.x; acc[15] += p.y;
                }
            }
        }
    }

    {   // write M'/Kf' (pre-scaled by own inv_deg)
        float inv = inv_deg[node];
        uint4 st;
        st.x = pack4fp8(acc[0] * inv,  acc[1] * inv,  acc[2] * inv,  acc[3] * inv);
        st.y = pack4fp8(acc[4] * inv,  acc[5] * inv,  acc[6] * inv,  acc[7] * inv);
        st.z = pack4fp8(acc[8] * inv,  acc[9] * inv,  acc[10] * inv, acc[11] * inv);
        st.w = pack4fp8(acc[12] * inv, acc[13] * inv, acc[14] * inv, acc[15] * inv);
        *(uint4*)(Mnew + (size_t)node * MSZ + lane * 16) = st;
        Kfnew[(size_t)node * 64 + lane] = f2bf(kacc * inv);
    }

    // C[h] = sum_i Q[h,i]*Kf[h,i]  — 16-lane allreduce within head group
    float c = qv * kacc;
    c += __shfl_xor(c, 1); c += __shfl_xor(c, 2); c += __shfl_xor(c, 4); c += __shfl_xor(c, 8);

    // H[h,j] = sum_i Q[h,i]*M[h,i,j] — reduce-scatter over the 16 i-lanes so
    // lane (h,i) ends holding H[h, j=i] (static indices only; no scratch).
    float w0[16];
    #pragma unroll
    for (int t = 0; t < 16; t++) w0[t] = qv * acc[t];
    float w1r[8];
    #pragma unroll
    for (int t = 0; t < 8; t++) {
        float a = w0[2 * t], b = w0[2 * t + 1];
        float mine = (lane & 1) ? b : a, th = (lane & 1) ? a : b;
        w1r[t] = mine + __shfl_xor(th, 1);
    }
    float w2r[4];
    #pragma unroll
    for (int t = 0; t < 4; t++) {
        float a = w1r[2 * t], b = w1r[2 * t + 1];
        float mine = (lane & 2) ? b : a, th = (lane & 2) ? a : b;
        w2r[t] = mine + __shfl_xor(th, 2);
    }
    float w3r[2];
    #pragma unroll
    for (int t = 0; t < 2; t++) {
        float a = w2r[2 * t], b = w2r[2 * t + 1];
        float mine = (lane & 4) ? b : a, th = (lane & 4) ? a : b;
        w3r[t] = mine + __shfl_xor(th, 4);
    }
    float Hv;
    {
        float a = w3r[0], b = w3r[1];
        float mine = (lane & 8) ? b : a, th = (lane & 8) ? a : b;
        Hv = mine + __shfl_xor(th, 8);
    }

    float g = gamma[hop * HEADS + grp];
    hidden[hoff] = hid_in + g * Hv / (c + CST);
}

// ---- push hop (hop 2): wave-per-SOURCE. Stream own M2'/Kf2' row once
// (nontemporal), gather dest Q (bf16, coalesced 128B), per-edge in-wave
// contraction (same reduce-scatter as pull), scatter via coalesced f32
// atomicAdd: 64 contiguous floats H[d] + 4 floats C[d]. ----
__global__ __launch_bounds__(128) void k_push(
    const unsigned char* __restrict__ Mb, const unsigned short* __restrict__ Kfb,
    const int* __restrict__ ocnt, const int* __restrict__ ocsr,
    const unsigned short* __restrict__ Qbf,
    float* __restrict__ Hp, float* __restrict__ Cp, int n) {
    int lane = threadIdx.x & 63;
    int node = blockIdx.x * 2 + (threadIdx.x >> 6);
    if (node >= n) return;
    int od = min(ocnt[node], SLOTS);
    int odU = __builtin_amdgcn_readfirstlane(od);
    if (odU == 0) return;
    int dsts = ocsr[(size_t)node * SLOTS + lane];      // all 64 out-slots
    // own row: lane (h=lane>>4, i=lane&15) holds M'[h,i,j], j=0..15
    u32x4 mraw = __builtin_nontemporal_load((const u32x4*)(Mb + (size_t)node * MSZ + lane * 16));
    float kf = bf2f(__builtin_nontemporal_load(Kfb + (size_t)node * 64 + lane));
    float mrow[16];
    {
        f32x2 p;
        p = __builtin_amdgcn_cvt_pk_f32_fp8((int)mraw.x, false); mrow[0]  = p.x; mrow[1]  = p.y;
        p = __builtin_amdgcn_cvt_pk_f32_fp8((int)mraw.x, true);  mrow[2]  = p.x; mrow[3]  = p.y;
        p = __builtin_amdgcn_cvt_pk_f32_fp8((int)mraw.y, false); mrow[4]  = p.x; mrow[5]  = p.y;
        p = __builtin_amdgcn_cvt_pk_f32_fp8((int)mraw.y, true);  mrow[6]  = p.x; mrow[7]  = p.y;
        p = __builtin_amdgcn_cvt_pk_f32_fp8((int)mraw.z, false); mrow[8]  = p.x; mrow[9]  = p.y;
        p = __builtin_amdgcn_cvt_pk_f32_fp8((int)mraw.z, true);  mrow[10] = p.x; mrow[11] = p.y;
        p = __builtin_amdgcn_cvt_pk_f32_fp8((int)mraw.w, false); mrow[12] = p.x; mrow[13] = p.y;
        p = __builtin_amdgcn_cvt_pk_f32_fp8((int)mraw.w, true);  mrow[14] = p.x; mrow[15] = p.y;
    }
    for (int base = 0; base < odU; base += 8) {
        int rem = odU - base;                          // wave-uniform
        float qv[8]; int dd[8];
        #pragma unroll
        for (int t = 0; t < 8; t++) {
            if (t < rem) {
                dd[t] = __builtin_amdgcn_readlane(dsts, base + t);
                qv[t] = bf2f(Qbf[(size_t)dd[t] * 64 + lane]);
            }
        }
        #pragma unroll
        for (int t = 0; t < 8; t++) {
            if (t < rem) {
                float q = qv[t];
                // C contribution: sum_i q[h,i]*kf[h,i] within 16-lane group
                float c = q * kf;
                c += __shfl_xor(c, 1); c += __shfl_xor(c, 2);
                c += __shfl_xor(c, 4); c += __shfl_xor(c, 8);
                // H contribution: reduce-scatter q*mrow over i-lanes
                float w0[16];
                #pragma unroll
                for (int k = 0; k < 16; k++) w0[k] = q * mrow[k];
                float w1r[8];
                #pragma unroll
                for (int k = 0; k < 8; k++) {
                    float a = w0[2 * k], b = w0[2 * k + 1];
                    float mine = (lane & 1) ? b : a, th = (lane & 1) ? a : b;
                    w1r[k] = mine + __shfl_xor(th, 1);
                }
                float w2r[4];
                #pragma unroll
                for (int k = 0; k < 4; k++) {
                    float a = w1r[2 * k], b = w1r[2 * k + 1];
                    float mine = (lane & 2) ? b : a, th = (lane & 2) ? a : b;
                    w2r[k] = mine + __shfl_xor(th, 2);
                }
                float w3r[2];
                #pragma unroll
                for (int k = 0; k < 2; k++) {
                    float a = w2r[2 * k], b = w2r[2 * k + 1];
                    float mine = (lane & 4) ? b : a, th = (lane & 4) ? a : b;
                    w3r[k] = mine + __shfl_xor(th, 4);
                }
                float Hv;
                {
                    float a = w3r[0], b = w3r[1];
                    float mine = (lane & 8) ? b : a, th = (lane & 8) ? a : b;
                    Hv = mine + __shfl_xor(th, 8);
                }
                atomicAdd(Hp + (size_t)dd[t] * 64 + lane, Hv);
                if ((lane & 15) == 0) atomicAdd(Cp + (size_t)dd[t] * 4 + (lane >> 4), c);
            }
        }
    }
}

// ---- combine: hid = hidden(post-hop1) + gamma2*H/C ; fused Wo proj + P1/P2 ----
__global__ __launch_bounds__(256) void k_comb(
    const float* __restrict__ hidden,
    const float* __restrict__ Hp, const float* __restrict__ Cp,
    const float* __restrict__ gamma,
    const float* __restrict__ Wo, const float* __restrict__ bo,
    const float* __restrict__ Wf1,
    float* __restrict__ out16, float* __restrict__ Pbuf, int n) {
    int lane = threadIdx.x & 63;
    int node = blockIdx.x * 4 + (threadIdx.x >> 6);
    if (node >= n) return;
    int h = lane >> 4;
    float H = Hp[(size_t)node * 64 + lane];
    float C = Cp[(size_t)node * 4 + h] + CST;
    float hid = hidden[(size_t)node * 64 + lane] + gamma[2 * HEADS + h] * H / C;
    // Wo projection: out16 = hid(64) @ Wo(64x16) + bo, reduced over 64 lanes
    const float4* wop = (const float4*)(Wo + lane * 16);
    float4 wo0 = wop[0], wo1 = wop[1], wo2 = wop[2], wo3 = wop[3];
    float v[16];
    v[0] = hid * wo0.x;  v[1] = hid * wo0.y;  v[2] = hid * wo0.z;  v[3] = hid * wo0.w;
    v[4] = hid * wo1.x;  v[5] = hid * wo1.y;  v[6] = hid * wo1.z;  v[7] = hid * wo1.w;
    v[8] = hid * wo2.x;  v[9] = hid * wo2.y;  v[10] = hid * wo2.z; v[11] = hid * wo2.w;
    v[12] = hid * wo3.x; v[13] = hid * wo3.y; v[14] = hid * wo3.z; v[15] = hid * wo3.w;
    #pragma unroll
    for (int m = 32; m >= 1; m >>= 1) {
        #pragma unroll
        for (int o = 0; o < 16; o++) v[o] += __shfl_xor(v[o], m);
    }
    #pragma unroll
    for (int o = 0; o < 16; o++) v[o] += bo[o];
    if (lane == 0) {
        float4* op = (float4*)(out16 + (size_t)node * 16);
        op[0] = make_float4(v[0],  v[1],  v[2],  v[3]);
        op[1] = make_float4(v[4],  v[5],  v[6],  v[7]);
        op[2] = make_float4(v[8],  v[9],  v[10], v[11]);
        op[3] = make_float4(v[12], v[13], v[14], v[15]);
    }
    if (lane < 32) {
        int o = lane & 15, half = lane >> 4;
        const float* wf = Wf1 + (size_t)(half * 16) * 16 + o;
        float p = 0.f;
        #pragma unroll
        for (int i = 0; i < 16; i++) p += v[i] * wf[i * 16];
        Pbuf[(size_t)node * 32 + lane] = p;         // [n][0:16]=P1(src), [16:32]=P2(dst)
    }
}

// ---------------- edge regression head: z = P1[s] + P2[d] + b1 ----------------
__global__ __launch_bounds__(256) void k_edge(
    const int* __restrict__ src, const int* __restrict__ dst,
    const float* __restrict__ Pbuf,
    const float* __restrict__ bf1, const float* __restrict__ Wf2,
    const float* __restrict__ bf2,
    float* __restrict__ out, int fe) {
    __shared__ float b1[16];
    __shared__ float w2[16];
    __shared__ float b2s;
    int t = threadIdx.x;
    if (t < 16) { b1[t] = bf1[t]; w2[t] = Wf2[t]; }
    if (t == 0) b2s = bf2[0];
    __syncthreads();
    int e = blockIdx.x * 256 + t;
    if (e >= fe) return;
    int s = src[e], d = dst[e];
    const float4* p1 = (const float4*)(Pbuf + (size_t)s * 32);
    const float4* p2 = (const float4*)(Pbuf + (size_t)d * 32 + 16);
    float z[16];
    #pragma unroll
    for (int q = 0; q < 4; q++) {
        float4 a = p1[q]; float4 b = p2[q];
        z[q * 4 + 0] = a.x + b.x; z[q * 4 + 1] = a.y + b.y;
        z[q * 4 + 2] = a.z + b.z; z[q * 4 + 3] = a.w + b.w;
    }
    float acc = b2s;
    #pragma unroll
    for (int o = 0; o < 16; o++) {
        float zz = z[o] + b1[o];
        zz = zz / (1.f + expf(-zz));       // silu
        acc += zz * w2[o];
    }
    out[e] = acc;
}

extern "C" void kernel_launch(void* const* d_in, const int* in_sizes, int n_in,
                              void* d_out, int out_size, void* d_ws, size_t ws_size,
                              hipStream_t stream) {
    const float* x        = (const float*)d_in[0];
    const int*   eidx     = (const int*)d_in[1];
    const int*   feidx    = (const int*)d_in[2];
    const int*   tsteps   = (const int*)d_in[3];
    const float* Wi  = (const float*)d_in[4];
    const float* bi  = (const float*)d_in[5];
    const float* Wt1 = (const float*)d_in[6];
    const float* bt1 = (const float*)d_in[7];
    const float* Wt2 = (const float*)d_in[8];
    const float* bt2 = (const float*)d_in[9];
    const float* WQ  = (const float*)d_in[10];
    const float* bQ  = (const float*)d_in[11];
    const float* WK  = (const float*)d_in[12];
    const float* bK  = (const float*)d_in[13];
    const float* WV  = (const float*)d_in[14];
    const float* bV  = (const float*)d_in[15];
    const float* Wo  = (const float*)d_in[16];
    const float* bo  = (const float*)d_in[17];
    const float* hopwise  = (const float*)d_in[18];
    const float* headwise = (const float*)d_in[19];
    const float* Wf1 = (const float*)d_in[20];
    const float* bf1 = (const float*)d_in[21];
    const float* Wf2 = (const float*)d_in[22];
    const float* bf2 = (const float*)d_in[23];

    const int N  = in_sizes[3];
    const int E  = in_sizes[1] / 2;
    const int FE = in_sizes[2] / 2;
    const int* row = eidx;           // [0,:]
    const int* col = eidx + E;       // [1,:]
    const int* fsrc = feidx;
    const int* fdst = feidx + FE;

    // ---- workspace carve-up (256B aligned) ----
    char* ws = (char*)d_ws;
    size_t off = 0;
    auto alloc = [&](size_t bytes) -> char* {
        char* p = ws + off;
        off = (off + bytes + 255) & ~(size_t)255;
        return p;
    };
    float* gamma     = (float*)alloc(KHOP * HEADS * sizeof(float));
    // zero-region (one memset): cnt, ocnt, Cp, Hp — keep contiguous
    int*   cnt       = (int*)alloc((size_t)N * 4);
    int*   ocnt      = (int*)alloc((size_t)N * 4);
    float* Cp        = (float*)alloc((size_t)N * 4 * 4);
    float* Hp        = (float*)alloc((size_t)N * 64 * 4);
    size_t zlen      = (size_t)((char*)(Hp + (size_t)N * 64) - (char*)cnt);
    int*   csr       = (int*)alloc((size_t)N * SLOTS * 4);
    int*   ocsr      = (int*)alloc((size_t)N * SLOTS * 4);
    float* inv_deg   = (float*)alloc((size_t)N * 4);
    float* temb      = (float*)alloc((size_t)NUM_T * HC * 4);
    float* Qbuf      = (float*)alloc((size_t)N * HC * 4);
    unsigned short* Qbf  = (unsigned short*)alloc((size_t)N * HC * 2);
    unsigned short* Kf0  = (unsigned short*)alloc((size_t)N * HC * 2);
    unsigned short* Kf_a = (unsigned short*)alloc((size_t)N * HC * 2);
    unsigned short* Kf_b = (unsigned short*)alloc((size_t)N * HC * 2);
    unsigned short* Vbuf = (unsigned short*)alloc((size_t)N * HC * 2);
    float* hidden    = (float*)alloc((size_t)N * HC * 4);
    unsigned char* M_a = (unsigned char*)alloc((size_t)N * MSZ);
    unsigned char* M_b = (unsigned char*)alloc((size_t)N * MSZ);
    float* Pbuf      = (float*)alloc((size_t)N * 32 * 4);
    (void)ws_size;

    float* out_edges = (float*)d_out;            // [FE]
    float* out_hid16 = (float*)d_out + FE;       // [N,16]

    const int miscBlocks = NUM_T + (N + 255) / 256;
    const int hopBlocks = (N + 1) / 2;

    (void)hipMemsetAsync(cnt, 0, zlen, stream);
    k_fill<<<(E + 255) / 256, 256, 0, stream>>>(row, col, cnt, csr, ocnt, ocsr, E);
    k_misc<<<miscBlocks, 256, 0, stream>>>(Wt1, bt1, Wt2, bt2, hopwise, headwise,
                                           cnt, gamma, temb, inv_deg, N);
    k_node<<<(N + 15) / 16, 256, 0, stream>>>(x, tsteps, temb, Wi, bi,
                                              WQ, bQ, WK, bK, WV, bV, hopwise, inv_deg,
                                              Qbuf, Qbf, Kf0, Vbuf, hidden, N);
    // hop 0 (pull, outer-product): Kf0'/V -> M_a', Kf_a', hidden += g0*H/C
    k_hop<0><<<hopBlocks, 128, 0, stream>>>(nullptr, Kf0, Vbuf, cnt, csr, inv_deg, Qbuf,
                                            gamma, M_a, Kf_a, hidden, 0, N);
    // hop 1 (pull, dense): M_a' -> M_b', Kf_b', hidden += g1*H/C
    k_hop<1><<<hopBlocks, 128, 0, stream>>>(M_a, Kf_a, nullptr, cnt, csr, inv_deg, Qbuf,
                                            gamma, M_b, Kf_b, hidden, 1, N);
    // hop 2 (push): stream M_b'/Kf_b' by source, scatter H/C atomics
    k_push<<<hopBlocks, 128, 0, stream>>>(M_b, Kf_b, ocnt, ocsr, Qbf, Hp, Cp, N);
    // combine -> hidden + g2*H/C -> Wo proj -> out16 + P1/P2
    k_comb<<<(N + 3) / 4, 256, 0, stream>>>(hidden, Hp, Cp, gamma, Wo, bo, Wf1,
                                            out_hid16, Pbuf, N);
    k_edge<<<(FE + 255) / 256, 256, 0, stream>>>(fsrc, fdst, Pbuf, bf1, Wf2, bf2,
                                                 out_edges, FE);
}

// Round 6
// 259.239 us; speedup vs baseline: 1.3574x; 1.1478x over previous
//
#include <hip/hip_runtime.h>
#include <math.h>

// MSTAGNN: N nodes, E edges (propagation), FE full edges (regression head).
// HC=64, HEADS=4, HEADC=DV=16, KHOP=3, NUM_T=128.
// R12 = R9 (best verified: wave-per-node pull hops, guarded tails, fused
// final-hop epilogue) consolidated: inv_deg buffer eliminated (computed from
// cnt at use sites), k_fill+k_misc merged into one k_pre dispatch, csr loads
// nontemporal in hops (single-use index stream; stop evicting M rows).
// Dense-hop pull measured pinned at ~2.1 TB/s scattered-miss service rate
// across 5 structures (LDS/wave-pull x2/XCD-sliced/push) — left untouched.

#define HC 64
#define HEADS 4
#define KHOP 3
#define NUM_T 128
#define MSZ 1024    // bytes per node M row (fp8)
#define SLOTS 64    // padded CSR slots per node
#define CST 1e-5f

typedef float f32x2 __attribute__((ext_vector_type(2)));

// ---- bf16 helpers (storage-only precision; accumulate in fp32) ----
__device__ __forceinline__ float bf2f(unsigned short s) { return __uint_as_float(((unsigned int)s) << 16); }
__device__ __forceinline__ float bfu_lo(unsigned int u) { return __uint_as_float(u << 16); }
__device__ __forceinline__ float bfu_hi(unsigned int u) { return __uint_as_float(u & 0xffff0000u); }
__device__ __forceinline__ unsigned short f2bf(float f) {
    unsigned int u = __float_as_uint(f);
    u = (u + 0x7fffu + ((u >> 16) & 1u)) >> 16;   // RTNE
    return (unsigned short)u;
}
// ---- fp8 e4m3 via HW pack/unpack (gfx950 OCP) ----
__device__ __forceinline__ unsigned int pack4fp8(float a, float b, float c, float d) {
    int r = __builtin_amdgcn_cvt_pk_fp8_f32(a, b, 0, false);       // bytes 0,1
    r = __builtin_amdgcn_cvt_pk_fp8_f32(c, d, r, true);            // bytes 2,3
    return (unsigned int)r;
}

// ---- k_pre: blocks [0,fillBlocks) = padded-CSR fill; blocks [fillBlocks,
//      fillBlocks+NUM_T) = temb table (one tval each) + gamma (first) ----
__global__ __launch_bounds__(256) void k_pre(
    const int* __restrict__ row, const int* __restrict__ col,
    int* __restrict__ cnt, int* __restrict__ csr, int E, int fillBlocks,
    const float* __restrict__ Wt1, const float* __restrict__ bt1,
    const float* __restrict__ Wt2, const float* __restrict__ bt2,
    const float* __restrict__ hopwise, const float* __restrict__ headwise,
    float* __restrict__ gamma, float* __restrict__ table) {
    int b = blockIdx.x;
    if (b < fillBlocks) {
        int e = b * 256 + threadIdx.x;
        if (e < E) {
            int c = col[e];
            int r = row[e];
            int k = atomicAdd(&cnt[c], 1);
            if (k < SLOTS) csr[c * SLOTS + k] = r;
        }
        return;
    }
    int tval = b - fillBlocks;                       // 0..127
    int t = threadIdx.x;
    if (tval == 0 && t == 0) {
        for (int k = 0; k < KHOP; k++) {
            float m = -1e30f;
            for (int h2 = 0; h2 < HEADS; h2++) m = fmaxf(m, headwise[h2 * KHOP + k]);
            float ex[HEADS]; float s = 0.f;
            for (int h2 = 0; h2 < HEADS; h2++) { ex[h2] = expf(headwise[h2 * KHOP + k] - m); s += ex[h2]; }
            for (int h2 = 0; h2 < HEADS; h2++) gamma[k * HEADS + h2] = hopwise[k + 1] * ex[h2] / s;
        }
    }
    __shared__ float emb_s[64];
    __shared__ float z1_s[256];
    __shared__ float ps_s[4][64];
    if (t < 64) {
        float tt = (float)tval * 31.25f;             // 4000/128
        float e;
        if (t < 32) e = sinf(tt * expf(-0.2971077539347156f * (float)t));
        else        e = cosf(tt * expf(-0.2971077539347156f * (float)(t - 32)));
        emb_s[t] = e;
    }
    __syncthreads();
    {   // z1[t] = silu(emb . Wt1[:,t] + bt1[t])
        float acc = bt1[t];
        #pragma unroll 8
        for (int i = 0; i < 64; i++) acc += emb_s[i] * Wt1[i * 256 + t];
        z1_s[t] = acc / (1.f + expf(-acc));
    }
    __syncthreads();
    {   // out[j] = z1 . Wt2[:,j] + bt2[j], split over 4 partials
        int j = t & 63, p = t >> 6;
        float acc = 0.f;
        #pragma unroll 8
        for (int i = 0; i < 64; i++) acc += z1_s[p * 64 + i] * Wt2[(p * 64 + i) * 64 + j];
        ps_s[p][j] = acc;
    }
    __syncthreads();
    if (t < 64)
        table[tval * 64 + t] = ps_s[0][t] + ps_s[1][t] + ps_s[2][t] + ps_s[3][t] + bt2[t];
}

// ---- fused node kernel: h -> QKV -> Q, pre-scaled Kf0'(bf16), V(bf16),
//      hidden init. inv_deg computed from cnt in-register. ----
__global__ __launch_bounds__(256) void k_node(
    const float* __restrict__ x, const int* __restrict__ time_steps,
    const float* __restrict__ temb, const float* __restrict__ Wi,
    const float* __restrict__ bi,
    const float* __restrict__ WQ, const float* __restrict__ bQ,
    const float* __restrict__ WK, const float* __restrict__ bK,
    const float* __restrict__ WV, const float* __restrict__ bV,
    const float* __restrict__ hopwise, const int* __restrict__ cnt,
    float* __restrict__ Q, unsigned short* __restrict__ Kf0,
    unsigned short* __restrict__ Vbuf, float* __restrict__ hidden, int n) {
    __shared__ float xs[16][128];                      // 8 KB
    __shared__ float hs[16][64];                       // 4 KB
    int j = threadIdx.x & 63;
    int slot = threadIdx.x >> 6;                       // wave id
    int nbase = blockIdx.x * 16;
    int nvalid = min(16, n - nbase);
    const float4* xg = (const float4*)(x + (size_t)nbase * 128);
    float4* xs4 = (float4*)&xs[0][0];
    for (int idx = threadIdx.x; idx < nvalid * 32; idx += 256) xs4[idx] = xg[idx];
    __syncthreads();
    int nl = slot * 4;
    {
        float acc[4];
        #pragma unroll
        for (int k = 0; k < 4; k++) acc[k] = 0.f;
        #pragma unroll 8
        for (int i = 0; i < 128; i++) {
            float w = Wi[i * 64 + j];
            #pragma unroll
            for (int k = 0; k < 4; k++) acc[k] += xs[nl + k][i] * w;
        }
        float bj = bi[j];
        #pragma unroll
        for (int k = 0; k < 4; k++) {
            int node = nbase + nl + k;
            float te = (node < n) ? temb[time_steps[node] * 64 + j] : 0.f;
            hs[nl + k][j] = fmaxf(acc[k] + bj + te, 0.f);
        }
    }
    __syncthreads();
    float aq[4], ak[4], av[4];
    #pragma unroll
    for (int k = 0; k < 4; k++) { aq[k] = bQ[j]; ak[k] = bK[j]; av[k] = bV[j]; }
    #pragma unroll 4
    for (int i = 0; i < 64; i++) {
        float wq = WQ[i * 64 + j], wk = WK[i * 64 + j], wv = WV[i * 64 + j];
        #pragma unroll
        for (int k = 0; k < 4; k++) {
            float hv = hs[nl + k][i];
            aq[k] += hv * wq; ak[k] += hv * wk; av[k] += hv * wv;
        }
    }
    float h0 = hopwise[0];
    #pragma unroll
    for (int k = 0; k < 4; k++) {
        int node = nbase + nl + k;
        if (node < n) {
            float q  = 1.f + ((aq[k] > 0.f) ? aq[k] : (expf(aq[k]) - 1.f));
            float kf = 1.f + ((ak[k] > 0.f) ? ak[k] : (expf(ak[k]) - 1.f));
            int dg = min(cnt[node], SLOTS);
            float inv = (dg > 0) ? 1.0f / (float)dg : 0.0f;
            Q[(size_t)node * 64 + j] = q;
            Kf0[(size_t)node * 64 + j] = f2bf(kf * inv);       // pre-scaled Kf'
            Vbuf[(size_t)node * 64 + j] = f2bf(av[k]);
            hidden[(size_t)node * 64 + j] = av[k] * h0;
        }
    }
}

// ---- hop: wave-per-node (64 lanes), no LDS, no barriers; 2 nodes/block.
// MODE 0: outer-product gather from Kf'(bf16) + V(bf16)  [hop 0]
// MODE 1: dense gather from M(fp8) rows                  [hops 1,2]
// Full DEPTH-groups + exact wave-uniform guarded tail (no duplicate loads).
template<int MODE>
__global__ __launch_bounds__(128) void k_hop(
    const unsigned char* __restrict__ Mold, const unsigned short* __restrict__ Kfold,
    const unsigned short* __restrict__ Vbuf,
    const int* __restrict__ cnt, const int* __restrict__ csr,
    const float* __restrict__ Q, const float* __restrict__ gamma,
    unsigned char* __restrict__ Mnew, unsigned short* __restrict__ Kfnew,
    float* __restrict__ hidden, int hop, int write_out,
    const float* __restrict__ Wo, const float* __restrict__ bo,
    const float* __restrict__ Wf1, float* __restrict__ out16,
    float* __restrict__ Pbuf, int n) {
    constexpr int DEPTH = (MODE == 0) ? 4 : 8;
    int lane = threadIdx.x & 63;
    int node = blockIdx.x * 2 + (threadIdx.x >> 6);
    if (node >= n) return;
    int grp = lane >> 4;                               // head h
    int deg = min(cnt[node], SLOTS);
    int sidx = __builtin_nontemporal_load(csr + (size_t)node * SLOTS + lane); // single-use index stream
    float qv = Q[(size_t)node * 64 + lane];
    size_t hoff = (size_t)node * 64 + lane;
    float hid_in = hidden[hoff];
    int degU = __builtin_amdgcn_readfirstlane(deg);
    float acc[16];
    #pragma unroll
    for (int t = 0; t < 16; t++) acc[t] = 0.f;
    float kacc = 0.f;

    int d = 0;
    for (; d + DEPTH <= degU; d += DEPTH) {
        unsigned short kraw[DEPTH];
        uint4 m0[DEPTH], m1[DEPTH];
        #pragma unroll
        for (int t = 0; t < DEPTH; t++) {
            int s = __builtin_amdgcn_readlane(sidx, d + t);   // SGPR base
            kraw[t] = Kfold[(size_t)s * 64 + lane];
            if constexpr (MODE == 0) {
                const uint4* vp = (const uint4*)((const unsigned char*)Vbuf + (size_t)s * 128 + grp * 32);
                m0[t] = vp[0]; m1[t] = vp[1];
            } else {
                m0[t] = *(const uint4*)(Mold + (size_t)s * MSZ + lane * 16);
            }
        }
        #pragma unroll
        for (int t = 0; t < DEPTH; t++) {
            float kf = bf2f(kraw[t]);
            kacc += kf;
            if constexpr (MODE == 0) {
                acc[0]  = fmaf(kf, bfu_lo(m0[t].x), acc[0]);
                acc[1]  = fmaf(kf, bfu_hi(m0[t].x), acc[1]);
                acc[2]  = fmaf(kf, bfu_lo(m0[t].y), acc[2]);
                acc[3]  = fmaf(kf, bfu_hi(m0[t].y), acc[3]);
                acc[4]  = fmaf(kf, bfu_lo(m0[t].z), acc[4]);
                acc[5]  = fmaf(kf, bfu_hi(m0[t].z), acc[5]);
                acc[6]  = fmaf(kf, bfu_lo(m0[t].w), acc[6]);
                acc[7]  = fmaf(kf, bfu_hi(m0[t].w), acc[7]);
                acc[8]  = fmaf(kf, bfu_lo(m1[t].x), acc[8]);
                acc[9]  = fmaf(kf, bfu_hi(m1[t].x), acc[9]);
                acc[10] = fmaf(kf, bfu_lo(m1[t].y), acc[10]);
                acc[11] = fmaf(kf, bfu_hi(m1[t].y), acc[11]);
                acc[12] = fmaf(kf, bfu_lo(m1[t].z), acc[12]);
                acc[13] = fmaf(kf, bfu_hi(m1[t].z), acc[13]);
                acc[14] = fmaf(kf, bfu_lo(m1[t].w), acc[14]);
                acc[15] = fmaf(kf, bfu_hi(m1[t].w), acc[15]);
            } else {
                f32x2 p;
                p = __builtin_amdgcn_cvt_pk_f32_fp8((int)m0[t].x, false); acc[0]  += p.x; acc[1]  += p.y;
                p = __builtin_amdgcn_cvt_pk_f32_fp8((int)m0[t].x, true);  acc[2]  += p.x; acc[3]  += p.y;
                p = __builtin_amdgcn_cvt_pk_f32_fp8((int)m0[t].y, false); acc[4]  += p.x; acc[5]  += p.y;
                p = __builtin_amdgcn_cvt_pk_f32_fp8((int)m0[t].y, true);  acc[6]  += p.x; acc[7]  += p.y;
                p = __builtin_amdgcn_cvt_pk_f32_fp8((int)m0[t].z, false); acc[8]  += p.x; acc[9]  += p.y;
                p = __builtin_amdgcn_cvt_pk_f32_fp8((int)m0[t].z, true);  acc[10] += p.x; acc[11] += p.y;
                p = __builtin_amdgcn_cvt_pk_f32_fp8((int)m0[t].w, false); acc[12] += p.x; acc[13] += p.y;
                p = __builtin_amdgcn_cvt_pk_f32_fp8((int)m0[t].w, true);  acc[14] += p.x; acc[15] += p.y;
            }
        }
    }
    // exact tail: slots guarded by wave-uniform branches (no dup loads)
    if (d < degU) {
        int rem = degU - d;                            // 1..DEPTH-1
        unsigned short kraw[DEPTH];
        uint4 m0[DEPTH], m1[DEPTH];
        #pragma unroll
        for (int t = 0; t < DEPTH - 1; t++) {
            if (t < rem) {
                int s = __builtin_amdgcn_readlane(sidx, d + t);
                kraw[t] = Kfold[(size_t)s * 64 + lane];
                if constexpr (MODE == 0) {
                    const uint4* vp = (const uint4*)((const unsigned char*)Vbuf + (size_t)s * 128 + grp * 32);
                    m0[t] = vp[0]; m1[t] = vp[1];
                } else {
                    m0[t] = *(const uint4*)(Mold + (size_t)s * MSZ + lane * 16);
                }
            }
        }
        #pragma unroll
        for (int t = 0; t < DEPTH - 1; t++) {
            if (t < rem) {
                float kf = bf2f(kraw[t]);
                kacc += kf;
                if constexpr (MODE == 0) {
                    acc[0]  = fmaf(kf, bfu_lo(m0[t].x), acc[0]);
                    acc[1]  = fmaf(kf, bfu_hi(m0[t].x), acc[1]);
                    acc[2]  = fmaf(kf, bfu_lo(m0[t].y), acc[2]);
                    acc[3]  = fmaf(kf, bfu_hi(m0[t].y), acc[3]);
                    acc[4]  = fmaf(kf, bfu_lo(m0[t].z), acc[4]);
                    acc[5]  = fmaf(kf, bfu_hi(m0[t].z), acc[5]);
                    acc[6]  = fmaf(kf, bfu_lo(m0[t].w), acc[6]);
                    acc[7]  = fmaf(kf, bfu_hi(m0[t].w), acc[7]);
                    acc[8]  = fmaf(kf, bfu_lo(m1[t].x), acc[8]);
                    acc[9]  = fmaf(kf, bfu_hi(m1[t].x), acc[9]);
                    acc[10] = fmaf(kf, bfu_lo(m1[t].y), acc[10]);
                    acc[11] = fmaf(kf, bfu_hi(m1[t].y), acc[11]);
                    acc[12] = fmaf(kf, bfu_lo(m1[t].z), acc[12]);
                    acc[13] = fmaf(kf, bfu_hi(m1[t].z), acc[13]);
                    acc[14] = fmaf(kf, bfu_lo(m1[t].w), acc[14]);
                    acc[15] = fmaf(kf, bfu_hi(m1[t].w), acc[15]);
                } else {
                    f32x2 p;
                    p = __builtin_amdgcn_cvt_pk_f32_fp8((int)m0[t].x, false); acc[0]  += p.x; acc[1]  += p.y;
                    p = __builtin_amdgcn_cvt_pk_f32_fp8((int)m0[t].x, true);  acc[2]  += p.x; acc[3]  += p.y;
                    p = __builtin_amdgcn_cvt_pk_f32_fp8((int)m0[t].y, false); acc[4]  += p.x; acc[5]  += p.y;
                    p = __builtin_amdgcn_cvt_pk_f32_fp8((int)m0[t].y, true);  acc[6]  += p.x; acc[7]  += p.y;
                    p = __builtin_amdgcn_cvt_pk_f32_fp8((int)m0[t].z, false); acc[8]  += p.x; acc[9]  += p.y;
                    p = __builtin_amdgcn_cvt_pk_f32_fp8((int)m0[t].z, true);  acc[10] += p.x; acc[11] += p.y;
                    p = __builtin_amdgcn_cvt_pk_f32_fp8((int)m0[t].w, false); acc[12] += p.x; acc[13] += p.y;
                    p = __builtin_amdgcn_cvt_pk_f32_fp8((int)m0[t].w, true);  acc[14] += p.x; acc[15] += p.y;
                }
            }
        }
    }

    if (write_out) {
        float inv = (degU > 0) ? 1.0f / (float)degU : 0.0f;   // own in-degree
        uint4 st;
        st.x = pack4fp8(acc[0] * inv,  acc[1] * inv,  acc[2] * inv,  acc[3] * inv);
        st.y = pack4fp8(acc[4] * inv,  acc[5] * inv,  acc[6] * inv,  acc[7] * inv);
        st.z = pack4fp8(acc[8] * inv,  acc[9] * inv,  acc[10] * inv, acc[11] * inv);
        st.w = pack4fp8(acc[12] * inv, acc[13] * inv, acc[14] * inv, acc[15] * inv);
        *(uint4*)(Mnew + (size_t)node * MSZ + lane * 16) = st;
        Kfnew[(size_t)node * 64 + lane] = f2bf(kacc * inv);
    }

    // C[h] = sum_i Q[h,i]*Kf[h,i]  — 16-lane allreduce within head group
    float c = qv * kacc;
    c += __shfl_xor(c, 1); c += __shfl_xor(c, 2); c += __shfl_xor(c, 4); c += __shfl_xor(c, 8);

    // H[h,j] = sum_i Q[h,i]*M[h,i,j] — reduce-scatter over the 16 i-lanes so
    // lane (h,i) ends holding H[h, j=i] (static indices only; no scratch).
    float w0[16];
    #pragma unroll
    for (int t = 0; t < 16; t++) w0[t] = qv * acc[t];
    float w1r[8];
    #pragma unroll
    for (int t = 0; t < 8; t++) {
        float a = w0[2 * t], b = w0[2 * t + 1];
        float mine = (lane & 1) ? b : a, th = (lane & 1) ? a : b;
        w1r[t] = mine + __shfl_xor(th, 1);
    }
    float w2r[4];
    #pragma unroll
    for (int t = 0; t < 4; t++) {
        float a = w1r[2 * t], b = w1r[2 * t + 1];
        float mine = (lane & 2) ? b : a, th = (lane & 2) ? a : b;
        w2r[t] = mine + __shfl_xor(th, 2);
    }
    float w3r[2];
    #pragma unroll
    for (int t = 0; t < 2; t++) {
        float a = w2r[2 * t], b = w2r[2 * t + 1];
        float mine = (lane & 4) ? b : a, th = (lane & 4) ? a : b;
        w3r[t] = mine + __shfl_xor(th, 4);
    }
    float Hv;
    {
        float a = w3r[0], b = w3r[1];
        float mine = (lane & 8) ? b : a, th = (lane & 8) ? a : b;
        Hv = mine + __shfl_xor(th, 8);
    }

    float g = gamma[hop * HEADS + grp];
    float contrib = g * Hv / (c + CST);
    if (write_out) {
        hidden[hoff] = hid_in + contrib;
    } else {
        // final hop: fused Wo projection + bo, plus per-node P1/P2 for edge head
        float hid = hid_in + contrib;
        const float4* wop = (const float4*)(Wo + lane * 16);
        float4 wo0 = wop[0], wo1 = wop[1], wo2 = wop[2], wo3 = wop[3];
        float v[16];
        v[0] = hid * wo0.x;  v[1] = hid * wo0.y;  v[2] = hid * wo0.z;  v[3] = hid * wo0.w;
        v[4] = hid * wo1.x;  v[5] = hid * wo1.y;  v[6] = hid * wo1.z;  v[7] = hid * wo1.w;
        v[8] = hid * wo2.x;  v[9] = hid * wo2.y;  v[10] = hid * wo2.z; v[11] = hid * wo2.w;
        v[12] = hid * wo3.x; v[13] = hid * wo3.y; v[14] = hid * wo3.z; v[15] = hid * wo3.w;
        #pragma unroll
        for (int m = 32; m >= 1; m >>= 1) {
            #pragma unroll
            for (int o = 0; o < 16; o++) v[o] += __shfl_xor(v[o], m);
        }
        #pragma unroll
        for (int o = 0; o < 16; o++) v[o] += bo[o];
        if (lane == 0) {
            float4* op = (float4*)(out16 + (size_t)node * 16);
            op[0] = make_float4(v[0],  v[1],  v[2],  v[3]);
            op[1] = make_float4(v[4],  v[5],  v[6],  v[7]);
            op[2] = make_float4(v[8],  v[9],  v[10], v[11]);
            op[3] = make_float4(v[12], v[13], v[14], v[15]);
        }
        if (lane < 32) {
            int o = lane & 15, half = lane >> 4;
            const float* wf = Wf1 + (size_t)(half * 16) * 16 + o;
            float p = 0.f;
            #pragma unroll
            for (int i = 0; i < 16; i++) p += v[i] * wf[i * 16];
            Pbuf[(size_t)node * 32 + lane] = p;         // [n][0:16]=P1(src), [16:32]=P2(dst)
        }
    }
}

// ---------------- edge regression head: z = P1[s] + P2[d] + b1 ----------------
__global__ __launch_bounds__(256) void k_edge(
    const int* __restrict__ src, const int* __restrict__ dst,
    const float* __restrict__ Pbuf,
    const float* __restrict__ bf1, const float* __restrict__ Wf2,
    const float* __restrict__ bf2,
    float* __restrict__ out, int fe) {
    __shared__ float b1[16];
    __shared__ float w2[16];
    __shared__ float b2s;
    int t = threadIdx.x;
    if (t < 16) { b1[t] = bf1[t]; w2[t] = Wf2[t]; }
    if (t == 0) b2s = bf2[0];
    __syncthreads();
    int e = blockIdx.x * 256 + t;
    if (e >= fe) return;
    int s = src[e], d = dst[e];
    const float4* p1 = (const float4*)(Pbuf + (size_t)s * 32);
    const float4* p2 = (const float4*)(Pbuf + (size_t)d * 32 + 16);
    float z[16];
    #pragma unroll
    for (int q = 0; q < 4; q++) {
        float4 a = p1[q]; float4 b = p2[q];
        z[q * 4 + 0] = a.x + b.x; z[q * 4 + 1] = a.y + b.y;
        z[q * 4 + 2] = a.z + b.z; z[q * 4 + 3] = a.w + b.w;
    }
    float acc = b2s;
    #pragma unroll
    for (int o = 0; o < 16; o++) {
        float zz = z[o] + b1[o];
        zz = zz / (1.f + expf(-zz));       // silu
        acc += zz * w2[o];
    }
    out[e] = acc;
}

extern "C" void kernel_launch(void* const* d_in, const int* in_sizes, int n_in,
                              void* d_out, int out_size, void* d_ws, size_t ws_size,
                              hipStream_t stream) {
    const float* x        = (const float*)d_in[0];
    const int*   eidx     = (const int*)d_in[1];
    const int*   feidx    = (const int*)d_in[2];
    const int*   tsteps   = (const int*)d_in[3];
    const float* Wi  = (const float*)d_in[4];
    const float* bi  = (const float*)d_in[5];
    const float* Wt1 = (const float*)d_in[6];
    const float* bt1 = (const float*)d_in[7];
    const float* Wt2 = (const float*)d_in[8];
    const float* bt2 = (const float*)d_in[9];
    const float* WQ  = (const float*)d_in[10];
    const float* bQ  = (const float*)d_in[11];
    const float* WK  = (const float*)d_in[12];
    const float* bK  = (const float*)d_in[13];
    const float* WV  = (const float*)d_in[14];
    const float* bV  = (const float*)d_in[15];
    const float* Wo  = (const float*)d_in[16];
    const float* bo  = (const float*)d_in[17];
    const float* hopwise  = (const float*)d_in[18];
    const float* headwise = (const float*)d_in[19];
    const float* Wf1 = (const float*)d_in[20];
    const float* bf1 = (const float*)d_in[21];
    const float* Wf2 = (const float*)d_in[22];
    const float* bf2 = (const float*)d_in[23];

    const int N  = in_sizes[3];
    const int E  = in_sizes[1] / 2;
    const int FE = in_sizes[2] / 2;
    const int* row = eidx;           // [0,:]
    const int* col = eidx + E;       // [1,:]
    const int* fsrc = feidx;
    const int* fdst = feidx + FE;

    // ---- workspace carve-up (256B aligned) ----
    char* ws = (char*)d_ws;
    size_t off = 0;
    auto alloc = [&](size_t bytes) -> char* {
        char* p = ws + off;
        off = (off + bytes + 255) & ~(size_t)255;
        return p;
    };
    float* gamma     = (float*)alloc(KHOP * HEADS * sizeof(float));
    int*   cnt       = (int*)alloc((size_t)N * 4);
    int*   csr       = (int*)alloc((size_t)N * SLOTS * 4);
    float* temb      = (float*)alloc((size_t)NUM_T * HC * 4);
    float* Qbuf      = (float*)alloc((size_t)N * HC * 4);
    unsigned short* Kf0  = (unsigned short*)alloc((size_t)N * HC * 2);
    unsigned short* Kf_a = (unsigned short*)alloc((size_t)N * HC * 2);
    unsigned short* Kf_b = (unsigned short*)alloc((size_t)N * HC * 2);
    unsigned short* Vbuf = (unsigned short*)alloc((size_t)N * HC * 2);
    float* hidden    = (float*)alloc((size_t)N * HC * 4);
    unsigned char* M_a = (unsigned char*)alloc((size_t)N * MSZ);
    unsigned char* M_b = (unsigned char*)alloc((size_t)N * MSZ);
    float* Pbuf      = (float*)alloc((size_t)N * 32 * 4);
    (void)ws_size;

    float* out_edges = (float*)d_out;            // [FE]
    float* out_hid16 = (float*)d_out + FE;       // [N,16]

    const int fillBlocks = (E + 255) / 256;
    const int preBlocks  = fillBlocks + NUM_T;
    const int hopBlocks  = (N + 1) / 2;

    (void)hipMemsetAsync(cnt, 0, (size_t)N * 4, stream);
    // fused: CSR fill + temb table + gamma (one dispatch)
    k_pre<<<preBlocks, 256, 0, stream>>>(row, col, cnt, csr, E, fillBlocks,
                                         Wt1, bt1, Wt2, bt2, hopwise, headwise,
                                         gamma, temb);
    k_node<<<(N + 15) / 16, 256, 0, stream>>>(x, tsteps, temb, Wi, bi,
                                              WQ, bQ, WK, bK, WV, bV, hopwise, cnt,
                                              Qbuf, Kf0, Vbuf, hidden, N);
    // hop 0: outer-product gather (Kf0', V) -> M_a', Kf_a'
    k_hop<0><<<hopBlocks, 128, 0, stream>>>(nullptr, Kf0, Vbuf, cnt, csr, Qbuf, gamma,
                                            M_a, Kf_a, hidden, 0, 1, Wo, bo, Wf1,
                                            out_hid16, Pbuf, N);
    // hop 1: dense M_a' -> M_b'
    k_hop<1><<<hopBlocks, 128, 0, stream>>>(M_a, Kf_a, nullptr, cnt, csr, Qbuf, gamma,
                                            M_b, Kf_b, hidden, 1, 1, Wo, bo, Wf1,
                                            out_hid16, Pbuf, N);
    // hop 2: dense gather M_b', no write, fused Wo projection + P1/P2
    k_hop<1><<<hopBlocks, 128, 0, stream>>>(M_b, Kf_b, nullptr, cnt, csr, Qbuf, gamma,
                                            M_a, Kf_a, hidden, 2, 0, Wo, bo, Wf1,
                                            out_hid16, Pbuf, N);
    k_edge<<<(FE + 255) / 256, 256, 0, stream>>>(fsrc, fdst, Pbuf, bf1, Wf2, bf2,
                                                 out_edges, FE);
}

// Round 7
// 251.515 us; speedup vs baseline: 1.3990x; 1.0307x over previous
//
#include <hip/hip_runtime.h>
#include <math.h>

// MSTAGNN: N nodes, E edges (propagation), FE full edges (regression head).
// HC=64, HEADS=4, HEADC=DV=16, KHOP=3, NUM_T=128.
// R13: dense hops use the R7 structure (2 nodes/block, 128 thr/node, 8B/lane,
// 4-deep, LDS epilogue) — measured best at 40.6us/hop, 64% occupancy, 2.13
// TB/s on the ~2.15 TB/s scattered-miss wall — grafted with the later wins:
// cnt-inline inv_deg and the fused Wo-projection + edge-head P1/P2 epilogue.
// Hop 0 stays the R12 outer-product wave-per-node form (L2-resident inputs).
// Nontemporal csr load reverted (R12: -1us/hop regression).

#define HC 64
#define HEADS 4
#define KHOP 3
#define NUM_T 128
#define MSZ 1024    // bytes per node M row (fp8)
#define SLOTS 64    // padded CSR slots per node
#define CST 1e-5f

typedef float f32x2 __attribute__((ext_vector_type(2)));

// ---- bf16 helpers (storage-only precision; accumulate in fp32) ----
__device__ __forceinline__ float bf2f(unsigned short s) { return __uint_as_float(((unsigned int)s) << 16); }
__device__ __forceinline__ float bfu_lo(unsigned int u) { return __uint_as_float(u << 16); }
__device__ __forceinline__ float bfu_hi(unsigned int u) { return __uint_as_float(u & 0xffff0000u); }
__device__ __forceinline__ unsigned short f2bf(float f) {
    unsigned int u = __float_as_uint(f);
    u = (u + 0x7fffu + ((u >> 16) & 1u)) >> 16;   // RTNE
    return (unsigned short)u;
}
// ---- fp8 e4m3 via HW pack/unpack (gfx950 OCP) ----
__device__ __forceinline__ unsigned int pack4fp8(float a, float b, float c, float d) {
    int r = __builtin_amdgcn_cvt_pk_fp8_f32(a, b, 0, false);       // bytes 0,1
    r = __builtin_amdgcn_cvt_pk_fp8_f32(c, d, r, true);            // bytes 2,3
    return (unsigned int)r;
}

// ---- k_pre: blocks [0,fillBlocks) = padded-CSR fill; blocks [fillBlocks,
//      fillBlocks+NUM_T) = temb table (one tval each) + gamma (first) ----
__global__ __launch_bounds__(256) void k_pre(
    const int* __restrict__ row, const int* __restrict__ col,
    int* __restrict__ cnt, int* __restrict__ csr, int E, int fillBlocks,
    const float* __restrict__ Wt1, const float* __restrict__ bt1,
    const float* __restrict__ Wt2, const float* __restrict__ bt2,
    const float* __restrict__ hopwise, const float* __restrict__ headwise,
    float* __restrict__ gamma, float* __restrict__ table) {
    int b = blockIdx.x;
    if (b < fillBlocks) {
        int e = b * 256 + threadIdx.x;
        if (e < E) {
            int c = col[e];
            int r = row[e];
            int k = atomicAdd(&cnt[c], 1);
            if (k < SLOTS) csr[c * SLOTS + k] = r;
        }
        return;
    }
    int tval = b - fillBlocks;                       // 0..127
    int t = threadIdx.x;
    if (tval == 0 && t == 0) {
        for (int k = 0; k < KHOP; k++) {
            float m = -1e30f;
            for (int h2 = 0; h2 < HEADS; h2++) m = fmaxf(m, headwise[h2 * KHOP + k]);
            float ex[HEADS]; float s = 0.f;
            for (int h2 = 0; h2 < HEADS; h2++) { ex[h2] = expf(headwise[h2 * KHOP + k] - m); s += ex[h2]; }
            for (int h2 = 0; h2 < HEADS; h2++) gamma[k * HEADS + h2] = hopwise[k + 1] * ex[h2] / s;
        }
    }
    __shared__ float emb_s[64];
    __shared__ float z1_s[256];
    __shared__ float ps_s[4][64];
    if (t < 64) {
        float tt = (float)tval * 31.25f;             // 4000/128
        float e;
        if (t < 32) e = sinf(tt * expf(-0.2971077539347156f * (float)t));
        else        e = cosf(tt * expf(-0.2971077539347156f * (float)(t - 32)));
        emb_s[t] = e;
    }
    __syncthreads();
    {   // z1[t] = silu(emb . Wt1[:,t] + bt1[t])
        float acc = bt1[t];
        #pragma unroll 8
        for (int i = 0; i < 64; i++) acc += emb_s[i] * Wt1[i * 256 + t];
        z1_s[t] = acc / (1.f + expf(-acc));
    }
    __syncthreads();
    {   // out[j] = z1 . Wt2[:,j] + bt2[j], split over 4 partials
        int j = t & 63, p = t >> 6;
        float acc = 0.f;
        #pragma unroll 8
        for (int i = 0; i < 64; i++) acc += z1_s[p * 64 + i] * Wt2[(p * 64 + i) * 64 + j];
        ps_s[p][j] = acc;
    }
    __syncthreads();
    if (t < 64)
        table[tval * 64 + t] = ps_s[0][t] + ps_s[1][t] + ps_s[2][t] + ps_s[3][t] + bt2[t];
}

// ---- fused node kernel: h -> QKV -> Q, pre-scaled Kf0'(bf16), V(bf16),
//      hidden init. inv_deg computed from cnt in-register. ----
__global__ __launch_bounds__(256) void k_node(
    const float* __restrict__ x, const int* __restrict__ time_steps,
    const float* __restrict__ temb, const float* __restrict__ Wi,
    const float* __restrict__ bi,
    const float* __restrict__ WQ, const float* __restrict__ bQ,
    const float* __restrict__ WK, const float* __restrict__ bK,
    const float* __restrict__ WV, const float* __restrict__ bV,
    const float* __restrict__ hopwise, const int* __restrict__ cnt,
    float* __restrict__ Q, unsigned short* __restrict__ Kf0,
    unsigned short* __restrict__ Vbuf, float* __restrict__ hidden, int n) {
    __shared__ float xs[16][128];                      // 8 KB
    __shared__ float hs[16][64];                       // 4 KB
    int j = threadIdx.x & 63;
    int slot = threadIdx.x >> 6;                       // wave id
    int nbase = blockIdx.x * 16;
    int nvalid = min(16, n - nbase);
    const float4* xg = (const float4*)(x + (size_t)nbase * 128);
    float4* xs4 = (float4*)&xs[0][0];
    for (int idx = threadIdx.x; idx < nvalid * 32; idx += 256) xs4[idx] = xg[idx];
    __syncthreads();
    int nl = slot * 4;
    {
        float acc[4];
        #pragma unroll
        for (int k = 0; k < 4; k++) acc[k] = 0.f;
        #pragma unroll 8
        for (int i = 0; i < 128; i++) {
            float w = Wi[i * 64 + j];
            #pragma unroll
            for (int k = 0; k < 4; k++) acc[k] += xs[nl + k][i] * w;
        }
        float bj = bi[j];
        #pragma unroll
        for (int k = 0; k < 4; k++) {
            int node = nbase + nl + k;
            float te = (node < n) ? temb[time_steps[node] * 64 + j] : 0.f;
            hs[nl + k][j] = fmaxf(acc[k] + bj + te, 0.f);
        }
    }
    __syncthreads();
    float aq[4], ak[4], av[4];
    #pragma unroll
    for (int k = 0; k < 4; k++) { aq[k] = bQ[j]; ak[k] = bK[j]; av[k] = bV[j]; }
    #pragma unroll 4
    for (int i = 0; i < 64; i++) {
        float wq = WQ[i * 64 + j], wk = WK[i * 64 + j], wv = WV[i * 64 + j];
        #pragma unroll
        for (int k = 0; k < 4; k++) {
            float hv = hs[nl + k][i];
            aq[k] += hv * wq; ak[k] += hv * wk; av[k] += hv * wv;
        }
    }
    float h0 = hopwise[0];
    #pragma unroll
    for (int k = 0; k < 4; k++) {
        int node = nbase + nl + k;
        if (node < n) {
            float q  = 1.f + ((aq[k] > 0.f) ? aq[k] : (expf(aq[k]) - 1.f));
            float kf = 1.f + ((ak[k] > 0.f) ? ak[k] : (expf(ak[k]) - 1.f));
            int dg = min(cnt[node], SLOTS);
            float inv = (dg > 0) ? 1.0f / (float)dg : 0.0f;
            Q[(size_t)node * 64 + j] = q;
            Kf0[(size_t)node * 64 + j] = f2bf(kf * inv);       // pre-scaled Kf'
            Vbuf[(size_t)node * 64 + j] = f2bf(av[k]);
            hidden[(size_t)node * 64 + j] = av[k] * h0;
        }
    }
}

// ---- hop 0: wave-per-node outer-product gather from Kf'(bf16) + V(bf16).
// No LDS, no barriers; 2 nodes/block (128 thr). Always writes M'/Kf'/hidden.
__global__ __launch_bounds__(128) void k_hop0(
    const unsigned short* __restrict__ Kfold, const unsigned short* __restrict__ Vbuf,
    const int* __restrict__ cnt, const int* __restrict__ csr,
    const float* __restrict__ Q, const float* __restrict__ gamma,
    unsigned char* __restrict__ Mnew, unsigned short* __restrict__ Kfnew,
    float* __restrict__ hidden, int n) {
    constexpr int DEPTH = 4;
    int lane = threadIdx.x & 63;
    int node = blockIdx.x * 2 + (threadIdx.x >> 6);
    if (node >= n) return;
    int grp = lane >> 4;                               // head h
    int deg = min(cnt[node], SLOTS);
    int sidx = csr[(size_t)node * SLOTS + lane];       // all 64 slots, one load
    float qv = Q[(size_t)node * 64 + lane];
    size_t hoff = (size_t)node * 64 + lane;
    float hid_in = hidden[hoff];
    int degU = __builtin_amdgcn_readfirstlane(deg);
    float acc[16];
    #pragma unroll
    for (int t = 0; t < 16; t++) acc[t] = 0.f;
    float kacc = 0.f;

    int d = 0;
    for (; d + DEPTH <= degU; d += DEPTH) {
        unsigned short kraw[DEPTH];
        uint4 m0[DEPTH], m1[DEPTH];
        #pragma unroll
        for (int t = 0; t < DEPTH; t++) {
            int s = __builtin_amdgcn_readlane(sidx, d + t);   // SGPR base
            kraw[t] = Kfold[(size_t)s * 64 + lane];
            const uint4* vp = (const uint4*)((const unsigned char*)Vbuf + (size_t)s * 128 + grp * 32);
            m0[t] = vp[0]; m1[t] = vp[1];
        }
        #pragma unroll
        for (int t = 0; t < DEPTH; t++) {
            float kf = bf2f(kraw[t]);
            kacc += kf;
            acc[0]  = fmaf(kf, bfu_lo(m0[t].x), acc[0]);
            acc[1]  = fmaf(kf, bfu_hi(m0[t].x), acc[1]);
            acc[2]  = fmaf(kf, bfu_lo(m0[t].y), acc[2]);
            acc[3]  = fmaf(kf, bfu_hi(m0[t].y), acc[3]);
            acc[4]  = fmaf(kf, bfu_lo(m0[t].z), acc[4]);
            acc[5]  = fmaf(kf, bfu_hi(m0[t].z), acc[5]);
            acc[6]  = fmaf(kf, bfu_lo(m0[t].w), acc[6]);
            acc[7]  = fmaf(kf, bfu_hi(m0[t].w), acc[7]);
            acc[8]  = fmaf(kf, bfu_lo(m1[t].x), acc[8]);
            acc[9]  = fmaf(kf, bfu_hi(m1[t].x), acc[9]);
            acc[10] = fmaf(kf, bfu_lo(m1[t].y), acc[10]);
            acc[11] = fmaf(kf, bfu_hi(m1[t].y), acc[11]);
            acc[12] = fmaf(kf, bfu_lo(m1[t].z), acc[12]);
            acc[13] = fmaf(kf, bfu_hi(m1[t].z), acc[13]);
            acc[14] = fmaf(kf, bfu_lo(m1[t].w), acc[14]);
            acc[15] = fmaf(kf, bfu_hi(m1[t].w), acc[15]);
        }
    }
    if (d < degU) {
        int rem = degU - d;                            // 1..DEPTH-1
        unsigned short kraw[DEPTH];
        uint4 m0[DEPTH], m1[DEPTH];
        #pragma unroll
        for (int t = 0; t < DEPTH - 1; t++) {
            if (t < rem) {
                int s = __builtin_amdgcn_readlane(sidx, d + t);
                kraw[t] = Kfold[(size_t)s * 64 + lane];
                const uint4* vp = (const uint4*)((const unsigned char*)Vbuf + (size_t)s * 128 + grp * 32);
                m0[t] = vp[0]; m1[t] = vp[1];
            }
        }
        #pragma unroll
        for (int t = 0; t < DEPTH - 1; t++) {
            if (t < rem) {
                float kf = bf2f(kraw[t]);
                kacc += kf;
                acc[0]  = fmaf(kf, bfu_lo(m0[t].x), acc[0]);
                acc[1]  = fmaf(kf, bfu_hi(m0[t].x), acc[1]);
                acc[2]  = fmaf(kf, bfu_lo(m0[t].y), acc[2]);
                acc[3]  = fmaf(kf, bfu_hi(m0[t].y), acc[3]);
                acc[4]  = fmaf(kf, bfu_lo(m0[t].z), acc[4]);
                acc[5]  = fmaf(kf, bfu_hi(m0[t].z), acc[5]);
                acc[6]  = fmaf(kf, bfu_lo(m0[t].w), acc[6]);
                acc[7]  = fmaf(kf, bfu_hi(m0[t].w), acc[7]);
                acc[8]  = fmaf(kf, bfu_lo(m1[t].x), acc[8]);
                acc[9]  = fmaf(kf, bfu_hi(m1[t].x), acc[9]);
                acc[10] = fmaf(kf, bfu_lo(m1[t].y), acc[10]);
                acc[11] = fmaf(kf, bfu_hi(m1[t].y), acc[11]);
                acc[12] = fmaf(kf, bfu_lo(m1[t].z), acc[12]);
                acc[13] = fmaf(kf, bfu_hi(m1[t].z), acc[13]);
                acc[14] = fmaf(kf, bfu_lo(m1[t].w), acc[14]);
                acc[15] = fmaf(kf, bfu_hi(m1[t].w), acc[15]);
            }
        }
    }

    {   // write M'/Kf' (pre-scaled by own in-degree)
        float inv = (degU > 0) ? 1.0f / (float)degU : 0.0f;
        uint4 st;
        st.x = pack4fp8(acc[0] * inv,  acc[1] * inv,  acc[2] * inv,  acc[3] * inv);
        st.y = pack4fp8(acc[4] * inv,  acc[5] * inv,  acc[6] * inv,  acc[7] * inv);
        st.z = pack4fp8(acc[8] * inv,  acc[9] * inv,  acc[10] * inv, acc[11] * inv);
        st.w = pack4fp8(acc[12] * inv, acc[13] * inv, acc[14] * inv, acc[15] * inv);
        *(uint4*)(Mnew + (size_t)node * MSZ + lane * 16) = st;
        Kfnew[(size_t)node * 64 + lane] = f2bf(kacc * inv);
    }

    // C[h] allreduce within head group
    float c = qv * kacc;
    c += __shfl_xor(c, 1); c += __shfl_xor(c, 2); c += __shfl_xor(c, 4); c += __shfl_xor(c, 8);

    // H[h,j] reduce-scatter over the 16 i-lanes (lane (h,i) ends with H[h,j=i])
    float w0[16];
    #pragma unroll
    for (int t = 0; t < 16; t++) w0[t] = qv * acc[t];
    float w1r[8];
    #pragma unroll
    for (int t = 0; t < 8; t++) {
        float a = w0[2 * t], b = w0[2 * t + 1];
        float mine = (lane & 1) ? b : a, th = (lane & 1) ? a : b;
        w1r[t] = mine + __shfl_xor(th, 1);
    }
    float w2r[4];
    #pragma unroll
    for (int t = 0; t < 4; t++) {
        float a = w1r[2 * t], b = w1r[2 * t + 1];
        float mine = (lane & 2) ? b : a, th = (lane & 2) ? a : b;
        w2r[t] = mine + __shfl_xor(th, 2);
    }
    float w3r[2];
    #pragma unroll
    for (int t = 0; t < 2; t++) {
        float a = w2r[2 * t], b = w2r[2 * t + 1];
        float mine = (lane & 4) ? b : a, th = (lane & 4) ? a : b;
        w3r[t] = mine + __shfl_xor(th, 4);
    }
    float Hv;
    {
        float a = w3r[0], b = w3r[1];
        float mine = (lane & 8) ? b : a, th = (lane & 8) ? a : b;
        Hv = mine + __shfl_xor(th, 8);
    }

    float g = gamma[0 * HEADS + grp];
    hidden[hoff] = hid_in + g * Hv / (c + CST);
}

// ---- dense hops 1,2 (R7 structure): 2 nodes/block, 128 thr/node; 8B/lane,
// 4 edges/iter (32B/thread in flight). LDS epilogue; low VGPR -> high occ.
// write_out=1: update hidden + write M'/Kf'. write_out=0: final — fused Wo
// projection (out16) + edge-head P1/P2 factorization into Pbuf.
__global__ __launch_bounds__(256) void k_dense(
    const unsigned char* __restrict__ Mold, const unsigned short* __restrict__ Kfold,
    const int* __restrict__ cnt, const int* __restrict__ csr,
    const float* __restrict__ Q, const float* __restrict__ gamma,
    unsigned char* __restrict__ Mnew, unsigned short* __restrict__ Kfnew,
    float* __restrict__ hidden, int hop, int write_out,
    const float* __restrict__ Wo, const float* __restrict__ bo,
    const float* __restrict__ Wf1, float* __restrict__ out16,
    float* __restrict__ Pbuf, int n) {
    int group = threadIdx.x >> 7;        // node slot within block (0/1)
    int gtid  = threadIdx.x & 127;       // thread within node group
    int node  = blockIdx.x * 2 + group;
    int off   = gtid * 8;                // this thread's 8 fp8 elements [off, off+8)
    __shared__ float sm[2][MSZ];         // 8 KB
    __shared__ float sk[2][64];
    __shared__ float sh[2][64];
    __shared__ float so[2][16];
    bool valid = (node < n);
    float acc[8];
    #pragma unroll
    for (int t = 0; t < 8; t++) acc[t] = 0.f;
    float kacc = 0.f;
    if (valid) {
        int deg = min(cnt[node], SLOTS);
        const int* lst = csr + (size_t)node * SLOTS;
        int d = 0;
        for (; d + 4 <= deg; d += 4) {
            int s0 = lst[d + 0], s1 = lst[d + 1], s2 = lst[d + 2], s3 = lst[d + 3];
            uint2 m0 = *(const uint2*)(Mold + (size_t)s0 * MSZ + off);
            uint2 m1 = *(const uint2*)(Mold + (size_t)s1 * MSZ + off);
            uint2 m2 = *(const uint2*)(Mold + (size_t)s2 * MSZ + off);
            uint2 m3 = *(const uint2*)(Mold + (size_t)s3 * MSZ + off);
            float kr0 = 0.f, kr1 = 0.f, kr2 = 0.f, kr3 = 0.f;
            if (gtid < 64) {
                kr0 = bf2f(Kfold[(size_t)s0 * 64 + gtid]);
                kr1 = bf2f(Kfold[(size_t)s1 * 64 + gtid]);
                kr2 = bf2f(Kfold[(size_t)s2 * 64 + gtid]);
                kr3 = bf2f(Kfold[(size_t)s3 * 64 + gtid]);
            }
            const uint2 mm[4] = {m0, m1, m2, m3};
            #pragma unroll
            for (int p = 0; p < 4; p++) {
                f32x2 q;
                q = __builtin_amdgcn_cvt_pk_f32_fp8((int)mm[p].x, false); acc[0] += q.x; acc[1] += q.y;
                q = __builtin_amdgcn_cvt_pk_f32_fp8((int)mm[p].x, true);  acc[2] += q.x; acc[3] += q.y;
                q = __builtin_amdgcn_cvt_pk_f32_fp8((int)mm[p].y, false); acc[4] += q.x; acc[5] += q.y;
                q = __builtin_amdgcn_cvt_pk_f32_fp8((int)mm[p].y, true);  acc[6] += q.x; acc[7] += q.y;
            }
            if (gtid < 64) kacc += (kr0 + kr1) + (kr2 + kr3);
        }
        for (; d < deg; d++) {
            int s = lst[d];
            uint2 mv = *(const uint2*)(Mold + (size_t)s * MSZ + off);
            f32x2 q;
            q = __builtin_amdgcn_cvt_pk_f32_fp8((int)mv.x, false); acc[0] += q.x; acc[1] += q.y;
            q = __builtin_amdgcn_cvt_pk_f32_fp8((int)mv.x, true);  acc[2] += q.x; acc[3] += q.y;
            q = __builtin_amdgcn_cvt_pk_f32_fp8((int)mv.y, false); acc[4] += q.x; acc[5] += q.y;
            q = __builtin_amdgcn_cvt_pk_f32_fp8((int)mv.y, true);  acc[6] += q.x; acc[7] += q.y;
            if (gtid < 64) kacc += bf2f(Kfold[(size_t)s * 64 + gtid]);
        }
        // stage + optional write-out
        float4* dst = (float4*)&sm[group][off];
        dst[0] = make_float4(acc[0], acc[1], acc[2], acc[3]);
        dst[1] = make_float4(acc[4], acc[5], acc[6], acc[7]);
        if (gtid < 64) sk[group][gtid] = kacc;
        if (write_out) {
            float inv = (deg > 0) ? 1.0f / (float)deg : 0.0f;
            uint2 st;
            st.x = pack4fp8(acc[0] * inv, acc[1] * inv, acc[2] * inv, acc[3] * inv);
            st.y = pack4fp8(acc[4] * inv, acc[5] * inv, acc[6] * inv, acc[7] * inv);
            *(uint2*)(Mnew + (size_t)node * MSZ + off) = st;
            if (gtid < 64) Kfnew[(size_t)node * 64 + gtid] = f2bf(kacc * inv);
        }
    }
    __syncthreads();
    if (valid && gtid < 64) {
        int hh = gtid >> 4, j = gtid & 15;
        const float* qn = Q + (size_t)node * 64 + hh * 16;
        float C = CST, H = 0.f;
        #pragma unroll
        for (int i = 0; i < 16; i++) {
            float qv = qn[i];
            C += qv * sk[group][hh * 16 + i];
            H += qv * sm[group][hh * 256 + i * 16 + j];
        }
        float g = gamma[hop * HEADS + hh];
        float hid = hidden[(size_t)node * 64 + gtid] + g * H / C;
        if (write_out) hidden[(size_t)node * 64 + gtid] = hid;
        else sh[group][gtid] = hid;              // final hop: feed fused projection
    }
    if (!write_out) {
        __syncthreads();
        if (valid && gtid < 16) {
            float a = bo[gtid];
            #pragma unroll 8
            for (int i = 0; i < 64; i++) a += sh[group][i] * Wo[i * 16 + gtid];
            out16[(size_t)node * 16 + gtid] = a;
            so[group][gtid] = a;
        }
        __syncthreads();
        if (valid && gtid < 32) {
            int o = gtid & 15, half = gtid >> 4;
            const float* wf = Wf1 + (size_t)(half * 16) * 16 + o;
            float p = 0.f;
            #pragma unroll
            for (int i = 0; i < 16; i++) p += so[group][i] * wf[i * 16];
            Pbuf[(size_t)node * 32 + gtid] = p;  // [n][0:16]=P1(src), [16:32]=P2(dst)
        }
    }
}

// ---------------- edge regression head: z = P1[s] + P2[d] + b1 ----------------
__global__ __launch_bounds__(256) void k_edge(
    const int* __restrict__ src, const int* __restrict__ dst,
    const float* __restrict__ Pbuf,
    const float* __restrict__ bf1, const float* __restrict__ Wf2,
    const float* __restrict__ bf2,
    float* __restrict__ out, int fe) {
    __shared__ float b1[16];
    __shared__ float w2[16];
    __shared__ float b2s;
    int t = threadIdx.x;
    if (t < 16) { b1[t] = bf1[t]; w2[t] = Wf2[t]; }
    if (t == 0) b2s = bf2[0];
    __syncthreads();
    int e = blockIdx.x * 256 + t;
    if (e >= fe) return;
    int s = src[e], d = dst[e];
    const float4* p1 = (const float4*)(Pbuf + (size_t)s * 32);
    const float4* p2 = (const float4*)(Pbuf + (size_t)d * 32 + 16);
    float z[16];
    #pragma unroll
    for (int q = 0; q < 4; q++) {
        float4 a = p1[q]; float4 b = p2[q];
        z[q * 4 + 0] = a.x + b.x; z[q * 4 + 1] = a.y + b.y;
        z[q * 4 + 2] = a.z + b.z; z[q * 4 + 3] = a.w + b.w;
    }
    float acc = b2s;
    #pragma unroll
    for (int o = 0; o < 16; o++) {
        float zz = z[o] + b1[o];
        zz = zz / (1.f + expf(-zz));       // silu
        acc += zz * w2[o];
    }
    out[e] = acc;
}

extern "C" void kernel_launch(void* const* d_in, const int* in_sizes, int n_in,
                              void* d_out, int out_size, void* d_ws, size_t ws_size,
                              hipStream_t stream) {
    const float* x        = (const float*)d_in[0];
    const int*   eidx     = (const int*)d_in[1];
    const int*   feidx    = (const int*)d_in[2];
    const int*   tsteps   = (const int*)d_in[3];
    const float* Wi  = (const float*)d_in[4];
    const float* bi  = (const float*)d_in[5];
    const float* Wt1 = (const float*)d_in[6];
    const float* bt1 = (const float*)d_in[7];
    const float* Wt2 = (const float*)d_in[8];
    const float* bt2 = (const float*)d_in[9];
    const float* WQ  = (const float*)d_in[10];
    const float* bQ  = (const float*)d_in[11];
    const float* WK  = (const float*)d_in[12];
    const float* bK  = (const float*)d_in[13];
    const float* WV  = (const float*)d_in[14];
    const float* bV  = (const float*)d_in[15];
    const float* Wo  = (const float*)d_in[16];
    const float* bo  = (const float*)d_in[17];
    const float* hopwise  = (const float*)d_in[18];
    const float* headwise = (const float*)d_in[19];
    const float* Wf1 = (const float*)d_in[20];
    const float* bf1 = (const float*)d_in[21];
    const float* Wf2 = (const float*)d_in[22];
    const float* bf2 = (const float*)d_in[23];

    const int N  = in_sizes[3];
    const int E  = in_sizes[1] / 2;
    const int FE = in_sizes[2] / 2;
    const int* row = eidx;           // [0,:]
    const int* col = eidx + E;       // [1,:]
    const int* fsrc = feidx;
    const int* fdst = feidx + FE;

    // ---- workspace carve-up (256B aligned) ----
    char* ws = (char*)d_ws;
    size_t off = 0;
    auto alloc = [&](size_t bytes) -> char* {
        char* p = ws + off;
        off = (off + bytes + 255) & ~(size_t)255;
        return p;
    };
    float* gamma     = (float*)alloc(KHOP * HEADS * sizeof(float));
    int*   cnt       = (int*)alloc((size_t)N * 4);
    int*   csr       = (int*)alloc((size_t)N * SLOTS * 4);
    float* temb      = (float*)alloc((size_t)NUM_T * HC * 4);
    float* Qbuf      = (float*)alloc((size_t)N * HC * 4);
    unsigned short* Kf0  = (unsigned short*)alloc((size_t)N * HC * 2);
    unsigned short* Kf_a = (unsigned short*)alloc((size_t)N * HC * 2);
    unsigned short* Kf_b = (unsigned short*)alloc((size_t)N * HC * 2);
    unsigned short* Vbuf = (unsigned short*)alloc((size_t)N * HC * 2);
    float* hidden    = (float*)alloc((size_t)N * HC * 4);
    unsigned char* M_a = (unsigned char*)alloc((size_t)N * MSZ);
    unsigned char* M_b = (unsigned char*)alloc((size_t)N * MSZ);
    float* Pbuf      = (float*)alloc((size_t)N * 32 * 4);
    (void)ws_size;

    float* out_edges = (float*)d_out;            // [FE]
    float* out_hid16 = (float*)d_out + FE;       // [N,16]

    const int fillBlocks = (E + 255) / 256;
    const int preBlocks  = fillBlocks + NUM_T;
    const int hopBlocks  = (N + 1) / 2;

    (void)hipMemsetAsync(cnt, 0, (size_t)N * 4, stream);
    // fused: CSR fill + temb table + gamma (one dispatch)
    k_pre<<<preBlocks, 256, 0, stream>>>(row, col, cnt, csr, E, fillBlocks,
                                         Wt1, bt1, Wt2, bt2, hopwise, headwise,
                                         gamma, temb);
    k_node<<<(N + 15) / 16, 256, 0, stream>>>(x, tsteps, temb, Wi, bi,
                                              WQ, bQ, WK, bK, WV, bV, hopwise, cnt,
                                              Qbuf, Kf0, Vbuf, hidden, N);
    // hop 0: outer-product gather (Kf0', V) -> M_a', Kf_a'
    k_hop0<<<hopBlocks, 128, 0, stream>>>(Kf0, Vbuf, cnt, csr, Qbuf, gamma,
                                          M_a, Kf_a, hidden, N);
    // hop 1 (dense, R7 structure): M_a' -> M_b'
    k_dense<<<hopBlocks, 256, 0, stream>>>(M_a, Kf_a, cnt, csr, Qbuf, gamma,
                                           M_b, Kf_b, hidden, 1, 1, Wo, bo, Wf1,
                                           out_hid16, Pbuf, N);
    // hop 2 (dense, final): gather M_b', fused Wo projection + P1/P2
    k_dense<<<hopBlocks, 256, 0, stream>>>(M_b, Kf_b, cnt, csr, Qbuf, gamma,
                                           M_a, Kf_a, hidden, 2, 0, Wo, bo, Wf1,
                                           out_hid16, Pbuf, N);
    k_edge<<<(FE + 255) / 256, 256, 0, stream>>>(fsrc, fdst, Pbuf, bf1, Wf2, bf2,
                                                 out_edges, FE);
}